// Round 1
// baseline (4339.459 us; speedup 1.0000x reference)
//
#include <hip/hip_runtime.h>
#include <math.h>

#define S 256
#define NB 4
#define TAU 0.1f
#define KSEL 128
#define LOG_TAB 21
#define TAB_SZ (1u << LOG_TAB)
#define TAB_MASK (TAB_SZ - 1)
#define EMPTY64 0xFFFFFFFFFFFFFFFFull

typedef unsigned long long u64;
typedef unsigned int u32;

__device__ __forceinline__ u32 hash_key(int key) {
    u32 h = (u32)key * 0x9E3779B1u;
    h ^= h >> 15;
    return h & TAB_MASK;
}

__global__ void k_init(u64* __restrict__ tab, int* __restrict__ cnt) {
    int i = blockIdx.x * blockDim.x + threadIdx.x;
    if (i < (int)TAB_SZ) tab[i] = EMPTY64;
    if (i < NB) cnt[i] = 0;
}

__global__ void k_insert(const int* __restrict__ coords, u64* __restrict__ tab, int N) {
    int i = blockIdx.x * blockDim.x + threadIdx.x;
    if (i >= N) return;
    int4 c = ((const int4*)coords)[i];
    int key = ((c.x * S + c.y) * S + c.z) * S + c.w;
    u64 ins = ((u64)(u32)key << 32) | (u32)i;
    u32 slot = hash_key(key);
    for (;;) {
        u64 e = tab[slot];
        if ((u32)(e >> 32) == (u32)key) { atomicMin(&tab[slot], ins); return; }
        if (e == EMPTY64) {
            u64 prev = atomicCAS(&tab[slot], EMPTY64, ins);
            if (prev == EMPTY64) return;
            if ((u32)(prev >> 32) == (u32)key) { atomicMin(&tab[slot], ins); return; }
        }
        slot = (slot + 1) & TAB_MASK;
    }
}

__device__ __forceinline__ int tab_lookup(const u64* __restrict__ tab, int key) {
    u32 slot = hash_key(key);
    for (;;) {
        u64 e = tab[slot];
        if ((u32)(e >> 32) == (u32)key) return (int)(u32)e;
        if (e == EMPTY64) return -1;
        slot = (slot + 1) & TAB_MASK;
    }
}

// Fused: neighbor-max -> peak detect+compact, and voxel_desc = l2norm(feats@W+b)
__global__ void k_main(const int* __restrict__ coords, const float* __restrict__ feats,
                       const float* __restrict__ scores, const float* __restrict__ W,
                       const float* __restrict__ bias, const u64* __restrict__ tab,
                       u64* __restrict__ peaks, int* __restrict__ cnt,
                       float* __restrict__ voxel_desc, int N) {
    int i = blockIdx.x * blockDim.x + threadIdx.x;
    if (i >= N) return;
    int4 c = ((const int4*)coords)[i];
    float conf = scores[i];
    int kb = ((c.x * S + c.y) * S + c.z) * S + c.w;
    float hmax = -INFINITY;
    #pragma unroll
    for (int dx = -1; dx <= 1; dx++) {
        int nx = c.y + dx;
        if (nx < 0 || nx >= S) continue;
        #pragma unroll
        for (int dy = -1; dy <= 1; dy++) {
            int ny = c.z + dy;
            if (ny < 0 || ny >= S) continue;
            #pragma unroll
            for (int dz = -1; dz <= 1; dz++) {
                int nz = c.w + dz;
                if (nz < 0 || nz >= S) continue;
                int j = tab_lookup(tab, kb + dx * S * S + dy * S + dz);
                if (j >= 0) {
                    float cj = scores[j];
                    if (cj > TAU) hmax = fmaxf(hmax, cj);
                }
            }
        }
    }
    if ((conf > TAU) && (hmax == conf)) {
        int p = atomicAdd(&cnt[c.x], 1);
        peaks[(size_t)c.x * N + p] = ((u64)__float_as_uint(conf) << 32) | (u32)(~(u32)i);
    }
    // voxel_desc row
    const float4* f4 = (const float4*)(feats + (size_t)i * 64);
    float acc[32];
    #pragma unroll
    for (int d = 0; d < 32; d++) acc[d] = bias[d];
    #pragma unroll
    for (int l4 = 0; l4 < 16; l4++) {
        float4 f = f4[l4];
        #pragma unroll
        for (int d = 0; d < 32; d++) {
            acc[d] = fmaf(f.x, W[(l4 * 4 + 0) * 32 + d], acc[d]);
            acc[d] = fmaf(f.y, W[(l4 * 4 + 1) * 32 + d], acc[d]);
            acc[d] = fmaf(f.z, W[(l4 * 4 + 2) * 32 + d], acc[d]);
            acc[d] = fmaf(f.w, W[(l4 * 4 + 3) * 32 + d], acc[d]);
        }
    }
    float ss = 0.f;
    #pragma unroll
    for (int d = 0; d < 32; d++) ss += acc[d] * acc[d];
    float inv = 1.0f / fmaxf(sqrtf(ss), 1e-12f);
    float4* out4 = (float4*)(voxel_desc + (size_t)i * 32);
    #pragma unroll
    for (int q = 0; q < 8; q++) {
        float4 o;
        o.x = acc[q * 4 + 0] * inv; o.y = acc[q * 4 + 1] * inv;
        o.z = acc[q * 4 + 2] * inv; o.w = acc[q * 4 + 3] * inv;
        out4[q] = o;
    }
}

// Per-batch exact top-K (value desc, index asc) via byte-wise radix select + bitonic sort.
__global__ void k_topk(u64* __restrict__ peaks, const int* __restrict__ cnt,
                       u64* __restrict__ bufA, u64* __restrict__ selected, int N) {
    int b = blockIdx.x;
    int tid = threadIdx.x;
    __shared__ int hist[256];
    __shared__ int sh_split, sh_above, sh_selc, sh_candc;
    u64* sel = selected + b * KSEL;
    u64* pcur = peaks + (size_t)b * N;
    u64* pnxt = bufA + (size_t)b * N;
    int n = cnt[b];
    int need = KSEL, nsel = 0;

    for (int byte = 7; byte >= 0; byte--) {
        if (need <= 0) break;
        if (n <= need) {
            for (int idx = tid; idx < n; idx += blockDim.x) sel[nsel + idx] = pcur[idx];
            nsel += n; need -= n; n = 0;
            break;
        }
        hist[tid] = 0;
        __syncthreads();
        int shift = byte * 8;
        for (int idx = tid; idx < n; idx += blockDim.x)
            atomicAdd(&hist[(int)((pcur[idx] >> shift) & 255)], 1);
        __syncthreads();
        if (tid == 0) {
            int above = 0, s = 255;
            for (; s > 0; s--) {
                if (above + hist[s] >= need) break;
                above += hist[s];
            }
            sh_split = s; sh_above = above; sh_selc = 0; sh_candc = 0;
        }
        __syncthreads();
        int s = sh_split;
        for (int idx = tid; idx < n; idx += blockDim.x) {
            u64 e = pcur[idx];
            int bv = (int)((e >> shift) & 255);
            if (bv > s) { int p = atomicAdd(&sh_selc, 1); sel[nsel + p] = e; }
            else if (bv == s) { int p = atomicAdd(&sh_candc, 1); pnxt[p] = e; }
        }
        __syncthreads();
        nsel += sh_above; need -= sh_above; n = sh_candc;
        u64* t = pcur; pcur = pnxt; pnxt = t;
        __syncthreads();
    }
    if (need > 0 && n > 0) {
        int take = need < n ? need : n;
        for (int idx = tid; idx < take; idx += blockDim.x) sel[nsel + idx] = pcur[idx];
        nsel += take;
    }
    for (int idx = nsel + tid; idx < KSEL; idx += blockDim.x) sel[idx] = 0;
    __syncthreads();

    // bitonic sort 128 keys, descending
    __shared__ u64 sk[KSEL];
    if (tid < KSEL) sk[tid] = sel[tid];
    __syncthreads();
    for (int k = 2; k <= KSEL; k <<= 1) {
        for (int j = k >> 1; j > 0; j >>= 1) {
            if (tid < KSEL) {
                int ixj = tid ^ j;
                if (ixj > tid) {
                    u64 a = sk[tid], c2 = sk[ixj];
                    bool upper = (tid & k) != 0;
                    // descending overall: swap if (a<c2) in "descending" segments
                    if (upper ? (a > c2) : (a < c2)) { sk[tid] = c2; sk[ixj] = a; }
                }
            }
            __syncthreads();
        }
    }
    if (tid < KSEL) sel[tid] = sk[tid];
}

// Finalize: peak_conf, cdesc rows (recompute favg for <=512 selected), background rows.
__global__ void k_final(const int* __restrict__ coords, const float* __restrict__ feats,
                        const float* __restrict__ scores, const float* __restrict__ W,
                        const float* __restrict__ bias, const float* __restrict__ background,
                        const u64* __restrict__ tab, const u64* __restrict__ selected,
                        float* __restrict__ out, int N) {
    int t = blockIdx.x * blockDim.x + threadIdx.x;
    float* peak_conf = out;
    float* full = out + NB * KSEL + (size_t)N * 32;
    if (t < NB * KSEL) {
        int b = t / KSEL, k = t % KSEL;
        u64 key = selected[t];
        float* row = full + (size_t)(b * (KSEL + 1) + 1 + k) * 32;
        if (key == 0ull) {
            peak_conf[t] = 0.f;
            for (int d = 0; d < 32; d++) row[d] = 0.f;
            return;
        }
        float conf = __uint_as_float((u32)(key >> 32));
        int i = (int)(~(u32)key);
        peak_conf[t] = conf;
        int4 c = ((const int4*)coords)[i];
        int kb = ((c.x * S + c.y) * S + c.z) * S + c.w;
        float fsum[64];
        #pragma unroll
        for (int l = 0; l < 64; l++) fsum[l] = 0.f;
        int c27 = 0;
        for (int dx = -1; dx <= 1; dx++) {
            int nx = c.y + dx;
            if (nx < 0 || nx >= S) continue;
            for (int dy = -1; dy <= 1; dy++) {
                int ny = c.z + dy;
                if (ny < 0 || ny >= S) continue;
                for (int dz = -1; dz <= 1; dz++) {
                    int nz = c.w + dz;
                    if (nz < 0 || nz >= S) continue;
                    int j = tab_lookup(tab, kb + dx * S * S + dy * S + dz);
                    if (j >= 0 && scores[j] > TAU) {
                        c27++;
                        const float4* nf = (const float4*)(feats + (size_t)j * 64);
                        #pragma unroll
                        for (int q = 0; q < 16; q++) {
                            float4 f = nf[q];
                            fsum[q * 4 + 0] += f.x; fsum[q * 4 + 1] += f.y;
                            fsum[q * 4 + 2] += f.z; fsum[q * 4 + 3] += f.w;
                        }
                    }
                }
            }
        }
        float invc = 1.0f / fmaxf((float)c27, 1.0f);
        float acc[32];
        #pragma unroll
        for (int d = 0; d < 32; d++) acc[d] = bias[d];
        #pragma unroll
        for (int l = 0; l < 64; l++) {
            float fv = fsum[l] * invc;
            #pragma unroll
            for (int d = 0; d < 32; d++) acc[d] = fmaf(fv, W[l * 32 + d], acc[d]);
        }
        float ss = 0.f;
        #pragma unroll
        for (int d = 0; d < 32; d++) ss += acc[d] * acc[d];
        float inv = 1.0f / fmaxf(sqrtf(ss), 1e-12f);
        for (int d = 0; d < 32; d++) row[d] = acc[d] * inv;
    } else if (t < NB * KSEL + NB * 32) {
        int idx = t - NB * KSEL;
        int b = idx / 32, d = idx % 32;
        full[(size_t)(b * (KSEL + 1)) * 32 + d] = background[d];
    }
}

extern "C" void kernel_launch(void* const* d_in, const int* in_sizes, int n_in,
                              void* d_out, int out_size, void* d_ws, size_t ws_size,
                              hipStream_t stream) {
    const int* coords = (const int*)d_in[0];
    const float* feats = (const float*)d_in[1];
    const float* scores = (const float*)d_in[2];
    const float* W = (const float*)d_in[3];
    const float* bias = (const float*)d_in[4];
    const float* background = (const float*)d_in[5];
    int N = in_sizes[0] / 4;
    float* out = (float*)d_out;

    char* ws = (char*)d_ws;
    size_t off = 0;
    u64* tab = (u64*)(ws + off); off += (size_t)TAB_SZ * 8;
    int* cnt = (int*)(ws + off); off += 256;
    u64* peaks = (u64*)(ws + off); off += (size_t)NB * N * 8;
    u64* bufA = (u64*)(ws + off); off += (size_t)NB * N * 8;
    u64* selected = (u64*)(ws + off); off += (size_t)NB * KSEL * 8;

    k_init<<<TAB_SZ / 256, 256, 0, stream>>>(tab, cnt);
    k_insert<<<(N + 255) / 256, 256, 0, stream>>>(coords, tab, N);
    k_main<<<(N + 255) / 256, 256, 0, stream>>>(coords, feats, scores, W, bias, tab,
                                                peaks, cnt, out + NB * KSEL, N);
    k_topk<<<NB, 256, 0, stream>>>(peaks, cnt, bufA, selected, N);
    k_final<<<6, 128, 0, stream>>>(coords, feats, scores, W, bias, background, tab,
                                   selected, out, N);
}

// Round 2
// 4297.541 us; speedup vs baseline: 1.0098x; 1.0098x over previous
//
#include <hip/hip_runtime.h>
#include <math.h>

#define S 256
#define NB 4
#define TAU 0.1f
#define KSEL 128
#define LOG_TAB 21
#define TAB_SZ (1u << LOG_TAB)
#define TAB_MASK (TAB_SZ - 1)
#define EMPTY64 0xFFFFFFFFFFFFFFFFull
#define BM_WORDS (1u << 21)   // 4*256^3 bits / 32

typedef unsigned long long u64;
typedef unsigned int u32;

__device__ __forceinline__ u32 hash_key(int key) {
    u32 h = (u32)key * 0x9E3779B1u;
    h ^= h >> 15;
    return h & TAB_MASK;
}

__global__ void k_init(u64* __restrict__ tab, u32* __restrict__ bm, int* __restrict__ cnt) {
    int i = blockIdx.x * blockDim.x + threadIdx.x;
    if (i < (int)TAB_SZ) tab[i] = EMPTY64;
    if (i < (int)BM_WORDS) bm[i] = 0u;
    if (i < NB) cnt[i] = 0;
}

__global__ void k_insert(const int* __restrict__ coords, u64* __restrict__ tab, int N) {
    int i = blockIdx.x * blockDim.x + threadIdx.x;
    if (i >= N) return;
    int4 c = ((const int4*)coords)[i];
    int key = ((c.x * S + c.y) * S + c.z) * S + c.w;
    u64 ins = ((u64)(u32)key << 32) | (u32)i;
    u32 slot = hash_key(key);
    for (;;) {
        u64 e = tab[slot];
        if ((u32)(e >> 32) == (u32)key) { atomicMin(&tab[slot], ins); return; }
        if (e == EMPTY64) {
            u64 prev = atomicCAS(&tab[slot], EMPTY64, ins);
            if (prev == EMPTY64) return;
            if ((u32)(prev >> 32) == (u32)key) { atomicMin(&tab[slot], ins); return; }
        }
        slot = (slot + 1) & TAB_MASK;
    }
}

// For each occupied slot: tabc[slot]=(key<<32)|conf_bits of representative; set bitmask if masked.
__global__ void k_tabpass(const float* __restrict__ scores, const u64* __restrict__ tab,
                          u64* __restrict__ tabc, u32* __restrict__ bm) {
    int s = blockIdx.x * blockDim.x + threadIdx.x;
    if (s >= (int)TAB_SZ) return;
    u64 e = tab[s];
    if (e == EMPTY64) { tabc[s] = EMPTY64; return; }
    u32 key = (u32)(e >> 32);
    int j = (int)(u32)e;
    float c = scores[j];
    tabc[s] = ((u64)key << 32) | __float_as_uint(c);
    if (c > TAU) atomicOr(&bm[key >> 5], 1u << (key & 31));
}

__device__ __forceinline__ int tab_lookup(const u64* __restrict__ tab, int key) {
    u32 slot = hash_key(key);
    for (;;) {
        u64 e = tab[slot];
        if ((u32)(e >> 32) == (u32)key) return (int)(u32)e;
        if (e == EMPTY64) return -1;
        slot = (slot + 1) & TAB_MASK;
    }
}

__device__ __forceinline__ float probe_conf(const u64* __restrict__ tabc, int key) {
    u32 slot = hash_key(key);
    for (;;) {
        u64 e = tabc[slot];
        if ((u32)(e >> 32) == (u32)key) return __uint_as_float((u32)e);
        if (e == EMPTY64) return -INFINITY;
        slot = (slot + 1) & TAB_MASK;
    }
}

// Fused: bitmask-filtered neighbor-max -> peak compact, and voxel_desc = l2norm(feats@W+b)
__global__ void k_main(const int* __restrict__ coords, const float* __restrict__ feats,
                       const float* __restrict__ scores, const float* __restrict__ W,
                       const float* __restrict__ bias, const u64* __restrict__ tabc,
                       const u32* __restrict__ bm,
                       u64* __restrict__ peaks, int* __restrict__ cnt,
                       float* __restrict__ voxel_desc, int N, int pcap) {
    int i = blockIdx.x * blockDim.x + threadIdx.x;
    if (i >= N) return;
    int4 c = ((const int4*)coords)[i];
    float conf = scores[i];
    int kb = ((c.x * S + c.y) * S + c.z) * S + c.w;

    if (conf > TAU) {
        // phase 1: 27 independent predicated bitmask tests
        u32 m27 = 0;
        int p = 0;
        #pragma unroll
        for (int dx = -1; dx <= 1; dx++) {
            bool vx = ((unsigned)(c.y + dx) < S);
            #pragma unroll
            for (int dy = -1; dy <= 1; dy++) {
                bool vy = ((unsigned)(c.z + dy) < S);
                int nk = kb + dx * (S * S) + dy * S;
                #pragma unroll
                for (int dz = -1; dz <= 1; dz++) {
                    bool vz = ((unsigned)(c.w + dz) < S);
                    if (vx && vy && vz) {
                        int nkz = nk + dz;
                        if ((bm[nkz >> 5] >> (nkz & 31)) & 1u) m27 |= (1u << p);
                    }
                    p++;
                }
            }
        }
        // phase 2: probe only occupied masked cells
        float hmax = -INFINITY;
        while (m27) {
            int q = __builtin_ctz(m27);
            m27 &= m27 - 1;
            int dx = q / 9 - 1;
            int r = q % 9;
            int dy = r / 3 - 1, dz = r % 3 - 1;
            float cj = probe_conf(tabc, kb + dx * (S * S) + dy * S + dz);
            hmax = fmaxf(hmax, cj);
        }
        if (hmax == conf) {
            int pidx = atomicAdd(&cnt[c.x], 1);
            if (pidx < pcap)
                peaks[(size_t)c.x * pcap + pidx] =
                    ((u64)__float_as_uint(conf) << 32) | (u32)(~(u32)i);
        }
    }

    // voxel_desc row
    const float4* f4 = (const float4*)(feats + (size_t)i * 64);
    float acc[32];
    #pragma unroll
    for (int d = 0; d < 32; d++) acc[d] = bias[d];
    #pragma unroll
    for (int l4 = 0; l4 < 16; l4++) {
        float4 f = f4[l4];
        #pragma unroll
        for (int d = 0; d < 32; d++) {
            acc[d] = fmaf(f.x, W[(l4 * 4 + 0) * 32 + d], acc[d]);
            acc[d] = fmaf(f.y, W[(l4 * 4 + 1) * 32 + d], acc[d]);
            acc[d] = fmaf(f.z, W[(l4 * 4 + 2) * 32 + d], acc[d]);
            acc[d] = fmaf(f.w, W[(l4 * 4 + 3) * 32 + d], acc[d]);
        }
    }
    float ss = 0.f;
    #pragma unroll
    for (int d = 0; d < 32; d++) ss += acc[d] * acc[d];
    float inv = 1.0f / fmaxf(sqrtf(ss), 1e-12f);
    float4* out4 = (float4*)(voxel_desc + (size_t)i * 32);
    #pragma unroll
    for (int q = 0; q < 8; q++) {
        float4 o;
        o.x = acc[q * 4 + 0] * inv; o.y = acc[q * 4 + 1] * inv;
        o.z = acc[q * 4 + 2] * inv; o.w = acc[q * 4 + 3] * inv;
        out4[q] = o;
    }
}

// Per-batch exact top-K (value desc, index asc) via byte-wise radix select + bitonic sort.
__global__ void k_topk(u64* __restrict__ peaks, const int* __restrict__ cnt,
                       u64* __restrict__ bufA, u64* __restrict__ selected, int pcap) {
    int b = blockIdx.x;
    int tid = threadIdx.x;
    __shared__ int hist[256];
    __shared__ int sh_split, sh_above, sh_selc, sh_candc;
    u64* sel = selected + b * KSEL;
    u64* pcur = peaks + (size_t)b * pcap;
    u64* pnxt = bufA + (size_t)b * pcap;
    int n = cnt[b];
    if (n > pcap) n = pcap;
    int need = KSEL, nsel = 0;

    for (int byte = 7; byte >= 0; byte--) {
        if (need <= 0) break;
        if (n <= need) {
            for (int idx = tid; idx < n; idx += blockDim.x) sel[nsel + idx] = pcur[idx];
            nsel += n; need -= n; n = 0;
            break;
        }
        hist[tid] = 0;
        __syncthreads();
        int shift = byte * 8;
        for (int idx = tid; idx < n; idx += blockDim.x)
            atomicAdd(&hist[(int)((pcur[idx] >> shift) & 255)], 1);
        __syncthreads();
        if (tid == 0) {
            int above = 0, s = 255;
            for (; s > 0; s--) {
                if (above + hist[s] >= need) break;
                above += hist[s];
            }
            sh_split = s; sh_above = above; sh_selc = 0; sh_candc = 0;
        }
        __syncthreads();
        int s = sh_split;
        for (int idx = tid; idx < n; idx += blockDim.x) {
            u64 e = pcur[idx];
            int bv = (int)((e >> shift) & 255);
            if (bv > s) { int p = atomicAdd(&sh_selc, 1); sel[nsel + p] = e; }
            else if (bv == s) { int p = atomicAdd(&sh_candc, 1); pnxt[p] = e; }
        }
        __syncthreads();
        nsel += sh_above; need -= sh_above; n = sh_candc;
        u64* t = pcur; pcur = pnxt; pnxt = t;
        __syncthreads();
    }
    if (need > 0 && n > 0) {
        int take = need < n ? need : n;
        for (int idx = tid; idx < take; idx += blockDim.x) sel[nsel + idx] = pcur[idx];
        nsel += take;
    }
    for (int idx = nsel + tid; idx < KSEL; idx += blockDim.x) sel[idx] = 0;
    __syncthreads();

    // bitonic sort 128 keys, descending
    __shared__ u64 sk[KSEL];
    if (tid < KSEL) sk[tid] = sel[tid];
    __syncthreads();
    for (int k = 2; k <= KSEL; k <<= 1) {
        for (int j = k >> 1; j > 0; j >>= 1) {
            if (tid < KSEL) {
                int ixj = tid ^ j;
                if (ixj > tid) {
                    u64 a = sk[tid], c2 = sk[ixj];
                    bool upper = (tid & k) != 0;
                    if (upper ? (a > c2) : (a < c2)) { sk[tid] = c2; sk[ixj] = a; }
                }
            }
            __syncthreads();
        }
    }
    if (tid < KSEL) sel[tid] = sk[tid];
}

// Finalize: peak_conf, cdesc rows (recompute favg for <=512 selected), background rows.
__global__ void k_final(const int* __restrict__ coords, const float* __restrict__ feats,
                        const float* __restrict__ scores, const float* __restrict__ W,
                        const float* __restrict__ bias, const float* __restrict__ background,
                        const u64* __restrict__ tab, const u64* __restrict__ selected,
                        float* __restrict__ out, int N) {
    int t = blockIdx.x * blockDim.x + threadIdx.x;
    float* peak_conf = out;
    float* full = out + NB * KSEL + (size_t)N * 32;
    if (t < NB * KSEL) {
        int b = t / KSEL, k = t % KSEL;
        u64 key = selected[t];
        float* row = full + (size_t)(b * (KSEL + 1) + 1 + k) * 32;
        if (key == 0ull) {
            peak_conf[t] = 0.f;
            for (int d = 0; d < 32; d++) row[d] = 0.f;
            return;
        }
        float conf = __uint_as_float((u32)(key >> 32));
        int i = (int)(~(u32)key);
        peak_conf[t] = conf;
        int4 c = ((const int4*)coords)[i];
        int kb = ((c.x * S + c.y) * S + c.z) * S + c.w;
        float fsum[64];
        #pragma unroll
        for (int l = 0; l < 64; l++) fsum[l] = 0.f;
        int c27 = 0;
        for (int dx = -1; dx <= 1; dx++) {
            int nx = c.y + dx;
            if (nx < 0 || nx >= S) continue;
            for (int dy = -1; dy <= 1; dy++) {
                int ny = c.z + dy;
                if (ny < 0 || ny >= S) continue;
                for (int dz = -1; dz <= 1; dz++) {
                    int nz = c.w + dz;
                    if (nz < 0 || nz >= S) continue;
                    int j = tab_lookup(tab, kb + dx * S * S + dy * S + dz);
                    if (j >= 0 && scores[j] > TAU) {
                        c27++;
                        const float4* nf = (const float4*)(feats + (size_t)j * 64);
                        #pragma unroll
                        for (int q = 0; q < 16; q++) {
                            float4 f = nf[q];
                            fsum[q * 4 + 0] += f.x; fsum[q * 4 + 1] += f.y;
                            fsum[q * 4 + 2] += f.z; fsum[q * 4 + 3] += f.w;
                        }
                    }
                }
            }
        }
        float invc = 1.0f / fmaxf((float)c27, 1.0f);
        float acc[32];
        #pragma unroll
        for (int d = 0; d < 32; d++) acc[d] = bias[d];
        #pragma unroll
        for (int l = 0; l < 64; l++) {
            float fv = fsum[l] * invc;
            #pragma unroll
            for (int d = 0; d < 32; d++) acc[d] = fmaf(fv, W[l * 32 + d], acc[d]);
        }
        float ss = 0.f;
        #pragma unroll
        for (int d = 0; d < 32; d++) ss += acc[d] * acc[d];
        float inv = 1.0f / fmaxf(sqrtf(ss), 1e-12f);
        for (int d = 0; d < 32; d++) row[d] = acc[d] * inv;
    } else if (t < NB * KSEL + NB * 32) {
        int idx = t - NB * KSEL;
        int b = idx / 32, d = idx % 32;
        full[(size_t)(b * (KSEL + 1)) * 32 + d] = background[d];
    }
}

extern "C" void kernel_launch(void* const* d_in, const int* in_sizes, int n_in,
                              void* d_out, int out_size, void* d_ws, size_t ws_size,
                              hipStream_t stream) {
    const int* coords = (const int*)d_in[0];
    const float* feats = (const float*)d_in[1];
    const float* scores = (const float*)d_in[2];
    const float* W = (const float*)d_in[3];
    const float* bias = (const float*)d_in[4];
    const float* background = (const float*)d_in[5];
    int N = in_sizes[0] / 4;
    float* out = (float*)d_out;
    int pcap = N / 2;

    char* ws = (char*)d_ws;
    size_t off = 0;
    u64* tab = (u64*)(ws + off); off += (size_t)TAB_SZ * 8;
    u64* tabc = (u64*)(ws + off); off += (size_t)TAB_SZ * 8;
    u32* bm = (u32*)(ws + off); off += (size_t)BM_WORDS * 4;
    int* cnt = (int*)(ws + off); off += 256;
    u64* peaks = (u64*)(ws + off); off += (size_t)NB * pcap * 8;
    u64* bufA = (u64*)(ws + off); off += (size_t)NB * pcap * 8;
    u64* selected = (u64*)(ws + off); off += (size_t)NB * KSEL * 8;

    k_init<<<TAB_SZ / 256, 256, 0, stream>>>(tab, bm, cnt);
    k_insert<<<(N + 255) / 256, 256, 0, stream>>>(coords, tab, N);
    k_tabpass<<<TAB_SZ / 256, 256, 0, stream>>>(scores, tab, tabc, bm);
    k_main<<<(N + 255) / 256, 256, 0, stream>>>(coords, feats, scores, W, bias, tabc, bm,
                                                peaks, cnt, out + NB * KSEL, N, pcap);
    k_topk<<<NB, 256, 0, stream>>>(peaks, cnt, bufA, selected, pcap);
    k_final<<<6, 128, 0, stream>>>(coords, feats, scores, W, bias, background, tab,
                                   selected, out, N);
}

// Round 3
// 1544.948 us; speedup vs baseline: 2.8088x; 2.7817x over previous
//
#include <hip/hip_runtime.h>
#include <math.h>

#define S 256
#define NB 4
#define TAU 0.1f
#define KSEL 128
#define LOG_TAB 21
#define TAB_SZ (1u << LOG_TAB)
#define TAB_MASK (TAB_SZ - 1)
#define EMPTY64 0xFFFFFFFFFFFFFFFFull
#define BM_WORDS (1u << 21)   // 4*256^3 bits / 32

typedef unsigned long long u64;
typedef unsigned int u32;

__device__ __forceinline__ u32 hash_key(int key) {
    u32 h = (u32)key * 0x9E3779B1u;
    h ^= h >> 15;
    return h & TAB_MASK;
}

__global__ void k_init(u64* __restrict__ tab, u32* __restrict__ bm, int* __restrict__ cnt) {
    int i = blockIdx.x * blockDim.x + threadIdx.x;
    if (i < (int)TAB_SZ) tab[i] = EMPTY64;
    if (i < (int)BM_WORDS) bm[i] = 0u;
    if (i < NB) cnt[i] = 0;
}

__global__ void k_insert(const int* __restrict__ coords, u64* __restrict__ tab, int N) {
    int i = blockIdx.x * blockDim.x + threadIdx.x;
    if (i >= N) return;
    int4 c = ((const int4*)coords)[i];
    int key = ((c.x * S + c.y) * S + c.z) * S + c.w;
    u64 ins = ((u64)(u32)key << 32) | (u32)i;
    u32 slot = hash_key(key);
    for (;;) {
        u64 e = tab[slot];
        if ((u32)(e >> 32) == (u32)key) { atomicMin(&tab[slot], ins); return; }
        if (e == EMPTY64) {
            u64 prev = atomicCAS(&tab[slot], EMPTY64, ins);
            if (prev == EMPTY64) return;
            if ((u32)(prev >> 32) == (u32)key) { atomicMin(&tab[slot], ins); return; }
        }
        slot = (slot + 1) & TAB_MASK;
    }
}

// For each occupied slot: tabc[slot]=(key<<32)|conf_bits of representative; set bitmask if masked.
__global__ void k_tabpass(const float* __restrict__ scores, const u64* __restrict__ tab,
                          u64* __restrict__ tabc, u32* __restrict__ bm) {
    int s = blockIdx.x * blockDim.x + threadIdx.x;
    if (s >= (int)TAB_SZ) return;
    u64 e = tab[s];
    if (e == EMPTY64) { tabc[s] = EMPTY64; return; }
    u32 key = (u32)(e >> 32);
    int j = (int)(u32)e;
    float c = scores[j];
    tabc[s] = ((u64)key << 32) | __float_as_uint(c);
    if (c > TAU) atomicOr(&bm[key >> 5], 1u << (key & 31));
}

__device__ __forceinline__ int tab_lookup(const u64* __restrict__ tab, int key) {
    u32 slot = hash_key(key);
    for (;;) {
        u64 e = tab[slot];
        if ((u32)(e >> 32) == (u32)key) return (int)(u32)e;
        if (e == EMPTY64) return -1;
        slot = (slot + 1) & TAB_MASK;
    }
}

__device__ __forceinline__ float probe_conf(const u64* __restrict__ tabc, int key) {
    u32 slot = hash_key(key);
    for (;;) {
        u64 e = tabc[slot];
        if ((u32)(e >> 32) == (u32)key) return __uint_as_float((u32)e);
        if (e == EMPTY64) return -INFINITY;
        slot = (slot + 1) & TAB_MASK;
    }
}

// Fused: bitmask-filtered neighbor-max -> wave-aggregated peak compact,
// and voxel_desc = l2norm(feats@W+b)
__global__ void k_main(const int* __restrict__ coords, const float* __restrict__ feats,
                       const float* __restrict__ scores, const float* __restrict__ W,
                       const float* __restrict__ bias, const u64* __restrict__ tabc,
                       const u32* __restrict__ bm,
                       u64* __restrict__ peaks, int* __restrict__ cnt,
                       float* __restrict__ voxel_desc, int N, int pcap) {
    int i = blockIdx.x * blockDim.x + threadIdx.x;
    bool alive = (i < N);
    int4 c = alive ? ((const int4*)coords)[i] : int4{0, 0, 0, 0};
    float conf = alive ? scores[i] : -INFINITY;
    int kb = ((c.x * S + c.y) * S + c.z) * S + c.w;

    bool ispeak = false;
    if (alive && conf > TAU) {
        // phase 1: 27 independent predicated bitmask tests
        u32 m27 = 0;
        int p = 0;
        #pragma unroll
        for (int dx = -1; dx <= 1; dx++) {
            bool vx = ((unsigned)(c.y + dx) < S);
            #pragma unroll
            for (int dy = -1; dy <= 1; dy++) {
                bool vy = ((unsigned)(c.z + dy) < S);
                int nk = kb + dx * (S * S) + dy * S;
                #pragma unroll
                for (int dz = -1; dz <= 1; dz++) {
                    bool vz = ((unsigned)(c.w + dz) < S);
                    if (vx && vy && vz) {
                        int nkz = nk + dz;
                        if ((bm[nkz >> 5] >> (nkz & 31)) & 1u) m27 |= (1u << p);
                    }
                    p++;
                }
            }
        }
        // phase 2: probe only occupied masked cells
        float hmax = -INFINITY;
        while (m27) {
            int q = __builtin_ctz(m27);
            m27 &= m27 - 1;
            int dx = q / 9 - 1;
            int r = q % 9;
            int dy = r / 3 - 1, dz = r % 3 - 1;
            float cj = probe_conf(tabc, kb + dx * (S * S) + dy * S + dz);
            hmax = fmaxf(hmax, cj);
        }
        ispeak = (hmax == conf);
    }

    // wave-aggregated compaction: <=4 global atomics per wave instead of 1 per peak
    int lane = threadIdx.x & 63;
    u64 lmask_lt = (lane == 63) ? 0x7FFFFFFFFFFFFFFFull : ((1ull << lane) - 1ull);
    #pragma unroll
    for (int b = 0; b < NB; b++) {
        u64 m = __ballot(ispeak && (c.x == b));
        if (m) {
            int leader = __ffsll((long long)m) - 1;
            int base = 0;
            if (lane == leader) base = atomicAdd(&cnt[b], __popcll(m));
            base = __shfl(base, leader);
            if (ispeak && c.x == b) {
                int rank = __popcll(m & lmask_lt);
                int pidx = base + rank;
                if (pidx < pcap)
                    peaks[(size_t)b * pcap + pidx] =
                        ((u64)__float_as_uint(conf) << 32) | (u32)(~(u32)i);
            }
        }
    }

    if (!alive) return;
    // voxel_desc row
    const float4* f4 = (const float4*)(feats + (size_t)i * 64);
    float acc[32];
    #pragma unroll
    for (int d = 0; d < 32; d++) acc[d] = bias[d];
    #pragma unroll
    for (int l4 = 0; l4 < 16; l4++) {
        float4 f = f4[l4];
        #pragma unroll
        for (int d = 0; d < 32; d++) {
            acc[d] = fmaf(f.x, W[(l4 * 4 + 0) * 32 + d], acc[d]);
            acc[d] = fmaf(f.y, W[(l4 * 4 + 1) * 32 + d], acc[d]);
            acc[d] = fmaf(f.z, W[(l4 * 4 + 2) * 32 + d], acc[d]);
            acc[d] = fmaf(f.w, W[(l4 * 4 + 3) * 32 + d], acc[d]);
        }
    }
    float ss = 0.f;
    #pragma unroll
    for (int d = 0; d < 32; d++) ss += acc[d] * acc[d];
    float inv = 1.0f / fmaxf(sqrtf(ss), 1e-12f);
    float4* out4 = (float4*)(voxel_desc + (size_t)i * 32);
    #pragma unroll
    for (int q = 0; q < 8; q++) {
        float4 o;
        o.x = acc[q * 4 + 0] * inv; o.y = acc[q * 4 + 1] * inv;
        o.z = acc[q * 4 + 2] * inv; o.w = acc[q * 4 + 3] * inv;
        out4[q] = o;
    }
}

// Per-batch exact top-K (value desc, index asc) via byte-wise radix select + bitonic sort.
__global__ void k_topk(u64* __restrict__ peaks, const int* __restrict__ cnt,
                       u64* __restrict__ bufA, u64* __restrict__ selected, int pcap) {
    int b = blockIdx.x;
    int tid = threadIdx.x;
    __shared__ int hist[256];
    __shared__ int sh_split, sh_above, sh_selc, sh_candc;
    u64* sel = selected + b * KSEL;
    u64* pcur = peaks + (size_t)b * pcap;
    u64* pnxt = bufA + (size_t)b * pcap;
    int n = cnt[b];
    if (n > pcap) n = pcap;
    int need = KSEL, nsel = 0;

    for (int byte = 7; byte >= 0; byte--) {
        if (need <= 0) break;
        if (n <= need) {
            for (int idx = tid; idx < n; idx += blockDim.x) sel[nsel + idx] = pcur[idx];
            nsel += n; need -= n; n = 0;
            break;
        }
        hist[tid] = 0;
        __syncthreads();
        int shift = byte * 8;
        for (int idx = tid; idx < n; idx += blockDim.x)
            atomicAdd(&hist[(int)((pcur[idx] >> shift) & 255)], 1);
        __syncthreads();
        if (tid == 0) {
            int above = 0, s = 255;
            for (; s > 0; s--) {
                if (above + hist[s] >= need) break;
                above += hist[s];
            }
            sh_split = s; sh_above = above; sh_selc = 0; sh_candc = 0;
        }
        __syncthreads();
        int s = sh_split;
        for (int idx = tid; idx < n; idx += blockDim.x) {
            u64 e = pcur[idx];
            int bv = (int)((e >> shift) & 255);
            if (bv > s) { int p = atomicAdd(&sh_selc, 1); sel[nsel + p] = e; }
            else if (bv == s) { int p = atomicAdd(&sh_candc, 1); pnxt[p] = e; }
        }
        __syncthreads();
        nsel += sh_above; need -= sh_above; n = sh_candc;
        u64* t = pcur; pcur = pnxt; pnxt = t;
        __syncthreads();
    }
    if (need > 0 && n > 0) {
        int take = need < n ? need : n;
        for (int idx = tid; idx < take; idx += blockDim.x) sel[nsel + idx] = pcur[idx];
        nsel += take;
    }
    for (int idx = nsel + tid; idx < KSEL; idx += blockDim.x) sel[idx] = 0;
    __syncthreads();

    // bitonic sort 128 keys, descending
    __shared__ u64 sk[KSEL];
    if (tid < KSEL) sk[tid] = sel[tid];
    __syncthreads();
    for (int k = 2; k <= KSEL; k <<= 1) {
        for (int j = k >> 1; j > 0; j >>= 1) {
            if (tid < KSEL) {
                int ixj = tid ^ j;
                if (ixj > tid) {
                    u64 a = sk[tid], c2 = sk[ixj];
                    bool upper = (tid & k) != 0;
                    if (upper ? (a > c2) : (a < c2)) { sk[tid] = c2; sk[ixj] = a; }
                }
            }
            __syncthreads();
        }
    }
    if (tid < KSEL) sel[tid] = sk[tid];
}

// Finalize: peak_conf, cdesc rows (recompute favg for <=512 selected), background rows.
__global__ void k_final(const int* __restrict__ coords, const float* __restrict__ feats,
                        const float* __restrict__ scores, const float* __restrict__ W,
                        const float* __restrict__ bias, const float* __restrict__ background,
                        const u64* __restrict__ tab, const u64* __restrict__ selected,
                        float* __restrict__ out, int N) {
    int t = blockIdx.x * blockDim.x + threadIdx.x;
    float* peak_conf = out;
    float* full = out + NB * KSEL + (size_t)N * 32;
    if (t < NB * KSEL) {
        int b = t / KSEL, k = t % KSEL;
        u64 key = selected[t];
        float* row = full + (size_t)(b * (KSEL + 1) + 1 + k) * 32;
        if (key == 0ull) {
            peak_conf[t] = 0.f;
            for (int d = 0; d < 32; d++) row[d] = 0.f;
            return;
        }
        float conf = __uint_as_float((u32)(key >> 32));
        int i = (int)(~(u32)key);
        peak_conf[t] = conf;
        int4 c = ((const int4*)coords)[i];
        int kb = ((c.x * S + c.y) * S + c.z) * S + c.w;
        float fsum[64];
        #pragma unroll
        for (int l = 0; l < 64; l++) fsum[l] = 0.f;
        int c27 = 0;
        for (int dx = -1; dx <= 1; dx++) {
            int nx = c.y + dx;
            if (nx < 0 || nx >= S) continue;
            for (int dy = -1; dy <= 1; dy++) {
                int ny = c.z + dy;
                if (ny < 0 || ny >= S) continue;
                for (int dz = -1; dz <= 1; dz++) {
                    int nz = c.w + dz;
                    if (nz < 0 || nz >= S) continue;
                    int j = tab_lookup(tab, kb + dx * S * S + dy * S + dz);
                    if (j >= 0 && scores[j] > TAU) {
                        c27++;
                        const float4* nf = (const float4*)(feats + (size_t)j * 64);
                        #pragma unroll
                        for (int q = 0; q < 16; q++) {
                            float4 f = nf[q];
                            fsum[q * 4 + 0] += f.x; fsum[q * 4 + 1] += f.y;
                            fsum[q * 4 + 2] += f.z; fsum[q * 4 + 3] += f.w;
                        }
                    }
                }
            }
        }
        float invc = 1.0f / fmaxf((float)c27, 1.0f);
        float acc[32];
        #pragma unroll
        for (int d = 0; d < 32; d++) acc[d] = bias[d];
        #pragma unroll
        for (int l = 0; l < 64; l++) {
            float fv = fsum[l] * invc;
            #pragma unroll
            for (int d = 0; d < 32; d++) acc[d] = fmaf(fv, W[l * 32 + d], acc[d]);
        }
        float ss = 0.f;
        #pragma unroll
        for (int d = 0; d < 32; d++) ss += acc[d] * acc[d];
        float inv = 1.0f / fmaxf(sqrtf(ss), 1e-12f);
        for (int d = 0; d < 32; d++) row[d] = acc[d] * inv;
    } else if (t < NB * KSEL + NB * 32) {
        int idx = t - NB * KSEL;
        int b = idx / 32, d = idx % 32;
        full[(size_t)(b * (KSEL + 1)) * 32 + d] = background[d];
    }
}

extern "C" void kernel_launch(void* const* d_in, const int* in_sizes, int n_in,
                              void* d_out, int out_size, void* d_ws, size_t ws_size,
                              hipStream_t stream) {
    const int* coords = (const int*)d_in[0];
    const float* feats = (const float*)d_in[1];
    const float* scores = (const float*)d_in[2];
    const float* W = (const float*)d_in[3];
    const float* bias = (const float*)d_in[4];
    const float* background = (const float*)d_in[5];
    int N = in_sizes[0] / 4;
    float* out = (float*)d_out;
    int pcap = N / 2;

    char* ws = (char*)d_ws;
    size_t off = 0;
    u64* tab = (u64*)(ws + off); off += (size_t)TAB_SZ * 8;
    u64* tabc = (u64*)(ws + off); off += (size_t)TAB_SZ * 8;
    u32* bm = (u32*)(ws + off); off += (size_t)BM_WORDS * 4;
    int* cnt = (int*)(ws + off); off += 256;
    u64* peaks = (u64*)(ws + off); off += (size_t)NB * pcap * 8;
    u64* bufA = (u64*)(ws + off); off += (size_t)NB * pcap * 8;
    u64* selected = (u64*)(ws + off); off += (size_t)NB * KSEL * 8;

    k_init<<<TAB_SZ / 256, 256, 0, stream>>>(tab, bm, cnt);
    k_insert<<<(N + 255) / 256, 256, 0, stream>>>(coords, tab, N);
    k_tabpass<<<TAB_SZ / 256, 256, 0, stream>>>(scores, tab, tabc, bm);
    k_main<<<(N + 255) / 256, 256, 0, stream>>>(coords, feats, scores, W, bias, tabc, bm,
                                                peaks, cnt, out + NB * KSEL, N, pcap);
    k_topk<<<NB, 256, 0, stream>>>(peaks, cnt, bufA, selected, pcap);
    k_final<<<6, 128, 0, stream>>>(coords, feats, scores, W, bias, background, tab,
                                   selected, out, N);
}

// Round 4
// 767.656 us; speedup vs baseline: 5.6529x; 2.0126x over previous
//
#include <hip/hip_runtime.h>
#include <math.h>

#define S 256
#define NB 4
#define TAU 0.1f
#define KSEL 128
#define LOG_TAB 21
#define TAB_SZ (1u << LOG_TAB)
#define TAB_MASK (TAB_SZ - 1)
#define EMPTY64 0xFFFFFFFFFFFFFFFFull
#define BM_WORDS (1u << 21)   // 4*256^3 bits / 32
#define NBINS 8192
#define BIN_BASE 0x3D800      // (0x3D800000 >> 12), conf floor 0.0625 < TAU
#define CAND_CAP 4096

typedef unsigned long long u64;
typedef unsigned int u32;

__device__ __forceinline__ u32 hash_key(int key) {
    u32 h = (u32)key * 0x9E3779B1u;
    h ^= h >> 15;
    return h & TAB_MASK;
}

__device__ __forceinline__ int conf_bin(float conf) {
    int bin = (int)(__float_as_uint(conf) >> 12) - BIN_BASE;
    return bin < 0 ? 0 : (bin > NBINS - 1 ? NBINS - 1 : bin);
}

__global__ void k_init(u64* __restrict__ tab, u32* __restrict__ bm, int* __restrict__ cnt,
                       int* __restrict__ hist, int* __restrict__ ccnt, u32* __restrict__ thrbin) {
    int i = blockIdx.x * blockDim.x + threadIdx.x;
    if (i < (int)TAB_SZ) tab[i] = EMPTY64;
    if (i < (int)BM_WORDS) bm[i] = 0u;
    if (i < NB * NBINS) hist[i] = 0;
    if (i < NB) { cnt[i] = 0; ccnt[i] = 0; thrbin[i] = 0; }
}

__global__ void k_insert(const int* __restrict__ coords, u64* __restrict__ tab, int N) {
    int i = blockIdx.x * blockDim.x + threadIdx.x;
    if (i >= N) return;
    int4 c = ((const int4*)coords)[i];
    int key = ((c.x * S + c.y) * S + c.z) * S + c.w;
    u64 ins = ((u64)(u32)key << 32) | (u32)i;
    u32 slot = hash_key(key);
    for (;;) {
        u64 e = tab[slot];
        if ((u32)(e >> 32) == (u32)key) { atomicMin(&tab[slot], ins); return; }
        if (e == EMPTY64) {
            u64 prev = atomicCAS(&tab[slot], EMPTY64, ins);
            if (prev == EMPTY64) return;
            if ((u32)(prev >> 32) == (u32)key) { atomicMin(&tab[slot], ins); return; }
        }
        slot = (slot + 1) & TAB_MASK;
    }
}

// tabc[slot]=(key<<32)|conf_bits of representative (min index); set bm bit if conf>TAU.
__global__ void k_tabpass(const float* __restrict__ scores, const u64* __restrict__ tab,
                          u64* __restrict__ tabc, u32* __restrict__ bm) {
    int s = blockIdx.x * blockDim.x + threadIdx.x;
    if (s >= (int)TAB_SZ) return;
    u64 e = tab[s];
    if (e == EMPTY64) { tabc[s] = EMPTY64; return; }
    u32 key = (u32)(e >> 32);
    int j = (int)(u32)e;
    float c = scores[j];
    tabc[s] = ((u64)key << 32) | __float_as_uint(c);
    if (c > TAU) atomicOr(&bm[key >> 5], 1u << (key & 31));
}

__device__ __forceinline__ int tab_lookup(const u64* __restrict__ tab, int key) {
    u32 slot = hash_key(key);
    for (;;) {
        u64 e = tab[slot];
        if ((u32)(e >> 32) == (u32)key) return (int)(u32)e;
        if (e == EMPTY64) return -1;
        slot = (slot + 1) & TAB_MASK;
    }
}

__device__ __forceinline__ float probe_conf(const u64* __restrict__ tabc, int key) {
    u32 slot = hash_key(key);
    for (;;) {
        u64 e = tabc[slot];
        if ((u32)(e >> 32) == (u32)key) return __uint_as_float((u32)e);
        if (e == EMPTY64) return -INFINITY;
        slot = (slot + 1) & TAB_MASK;
    }
}

// Fused: staged feats + z-packed bitmask peak detect + wave-agg compact + hist + voxel_desc
__global__ void k_main(const int* __restrict__ coords, const float* __restrict__ feats,
                       const float* __restrict__ scores, const float* __restrict__ W,
                       const float* __restrict__ bias, const u64* __restrict__ tabc,
                       const u32* __restrict__ bm,
                       u64* __restrict__ peaks, int* __restrict__ cnt, int* __restrict__ hist,
                       float* __restrict__ voxel_desc, int N, int pcap) {
    int i = blockIdx.x * blockDim.x + threadIdx.x;
    bool alive = (i < N);
    int ii = alive ? i : 0;
    int4 c = ((const int4*)coords)[ii];
    float conf = alive ? scores[ii] : -INFINITY;
    // stage first half of feats row so stream loads overlap the peak phase
    const float4* f4 = (const float4*)(feats + (size_t)ii * 64);
    float4 fa[8];
    #pragma unroll
    for (int q = 0; q < 8; q++) fa[q] = f4[q];

    int kb = ((c.x * S + c.y) * S + c.z) * S + c.w;
    bool ispeak = false;
    if (alive && conf > TAU) {
        u32 m27 = 0;
        u32 vzm = (u32)((c.w > 0) ? 1 : 0) | 2u | (u32)((c.w < S - 1) ? 4 : 0);
        #pragma unroll
        for (int dx = -1; dx <= 1; dx++) {
            if ((unsigned)(c.y + dx) >= S) continue;
            #pragma unroll
            for (int dy = -1; dy <= 1; dy++) {
                if ((unsigned)(c.z + dy) >= S) continue;
                int nk = kb + dx * (S * S) + dy * S;   // center-z key of this column
                u32 idx = (u32)nk >> 5;
                int sft = nk & 31;
                u32 w0 = bm[idx];
                u32 b3;
                if (sft >= 1 && sft <= 30) {
                    b3 = (w0 >> (sft - 1)) & 7u;
                } else if (sft == 0) {
                    u32 wm = (nk >= 32) ? bm[idx - 1] : 0u;
                    b3 = ((wm >> 31) & 1u) | ((w0 & 3u) << 1);
                } else { // sft == 31
                    u32 wp = (idx + 1 < BM_WORDS) ? bm[idx + 1] : 0u;
                    b3 = ((w0 >> 30) & 3u) | ((wp & 1u) << 2);
                }
                b3 &= vzm;
                int p = ((dx + 1) * 3 + (dy + 1)) * 3;
                m27 |= b3 << p;
            }
        }
        float hmax = -INFINITY;
        while (m27) {
            int q = __builtin_ctz(m27);
            m27 &= m27 - 1;
            int dx = q / 9 - 1;
            int r = q % 9;
            int dy = r / 3 - 1, dz = r % 3 - 1;
            float cj = probe_conf(tabc, kb + dx * (S * S) + dy * S + dz);
            hmax = fmaxf(hmax, cj);
        }
        ispeak = (hmax == conf);
    }

    if (ispeak) atomicAdd(&hist[c.x * NBINS + conf_bin(conf)], 1);

    // wave-aggregated compaction
    int lane = threadIdx.x & 63;
    u64 lmask_lt = (lane == 63) ? 0x7FFFFFFFFFFFFFFFull : ((1ull << lane) - 1ull);
    #pragma unroll
    for (int b = 0; b < NB; b++) {
        u64 m = __ballot(ispeak && (c.x == b));
        if (m) {
            int leader = __ffsll((long long)m) - 1;
            int base = 0;
            if (lane == leader) base = atomicAdd(&cnt[b], __popcll(m));
            base = __shfl(base, leader);
            if (ispeak && c.x == b) {
                int rank = __popcll(m & lmask_lt);
                int pidx = base + rank;
                if (pidx < pcap)
                    peaks[(size_t)b * pcap + pidx] =
                        ((u64)__float_as_uint(conf) << 32) | (u32)(~(u32)i);
            }
        }
    }

    if (!alive) return;
    // second half of feats + GEMV + l2norm
    float4 fb[8];
    #pragma unroll
    for (int q = 0; q < 8; q++) fb[q] = f4[8 + q];
    float acc[32];
    #pragma unroll
    for (int d = 0; d < 32; d++) acc[d] = bias[d];
    #pragma unroll
    for (int l4 = 0; l4 < 8; l4++) {
        float4 f = fa[l4];
        #pragma unroll
        for (int d = 0; d < 32; d++) {
            acc[d] = fmaf(f.x, W[(l4 * 4 + 0) * 32 + d], acc[d]);
            acc[d] = fmaf(f.y, W[(l4 * 4 + 1) * 32 + d], acc[d]);
            acc[d] = fmaf(f.z, W[(l4 * 4 + 2) * 32 + d], acc[d]);
            acc[d] = fmaf(f.w, W[(l4 * 4 + 3) * 32 + d], acc[d]);
        }
    }
    #pragma unroll
    for (int l4 = 0; l4 < 8; l4++) {
        float4 f = fb[l4];
        #pragma unroll
        for (int d = 0; d < 32; d++) {
            acc[d] = fmaf(f.x, W[(32 + l4 * 4 + 0) * 32 + d], acc[d]);
            acc[d] = fmaf(f.y, W[(32 + l4 * 4 + 1) * 32 + d], acc[d]);
            acc[d] = fmaf(f.z, W[(32 + l4 * 4 + 2) * 32 + d], acc[d]);
            acc[d] = fmaf(f.w, W[(32 + l4 * 4 + 3) * 32 + d], acc[d]);
        }
    }
    float ss = 0.f;
    #pragma unroll
    for (int d = 0; d < 32; d++) ss += acc[d] * acc[d];
    float inv = 1.0f / fmaxf(sqrtf(ss), 1e-12f);
    float4* out4 = (float4*)(voxel_desc + (size_t)i * 32);
    #pragma unroll
    for (int q = 0; q < 8; q++) {
        float4 o;
        o.x = acc[q * 4 + 0] * inv; o.y = acc[q * 4 + 1] * inv;
        o.z = acc[q * 4 + 2] * inv; o.w = acc[q * 4 + 3] * inv;
        out4[q] = o;
    }
}

// One block; wave b finds per-batch threshold bin (count of bins >= thr covers K).
__global__ void k_thresh(const int* __restrict__ hist, const int* __restrict__ cnt,
                         u32* __restrict__ thrbin, int pcap) {
    int w = threadIdx.x >> 6;
    int lane = threadIdx.x & 63;
    if (w >= NB) return;
    int n = cnt[w]; if (n > pcap) n = pcap;
    int need = n < KSEL ? n : KSEL;
    const int* h = hist + w * NBINS;
    int running = 0;
    u32 thr = 0;
    for (int hi = NBINS - 64; hi >= 0; hi -= 64) {
        int v = h[hi + lane];
        int s = v;   // inclusive suffix scan: s(lane) = sum_{l>=lane} v
        #pragma unroll
        for (int off = 1; off < 64; off <<= 1) {
            int o = __shfl_down(s, off);
            if (lane + off < 64) s += o;
        }
        int csum = __shfl(s, 0);
        if (running + csum >= need) {
            u64 m = __ballot(running + s >= need);
            int top = 63 - __builtin_clzll(m);
            thr = (u32)(hi + top);
            break;
        }
        running += csum;
    }
    if (lane == 0) thrbin[w] = thr;
}

__global__ void k_compact(const u64* __restrict__ peaks, const int* __restrict__ cnt,
                          const u32* __restrict__ thrbin, u64* __restrict__ cand,
                          int* __restrict__ ccnt, int pcap) {
    int t = blockIdx.x * blockDim.x + threadIdx.x;
    int b = t / pcap;
    if (b >= NB) return;
    int e = t % pcap;
    int n = cnt[b]; if (n > pcap) n = pcap;
    if (e >= n) return;
    u64 key = peaks[(size_t)b * pcap + e];
    float conf = __uint_as_float((u32)(key >> 32));
    if (conf_bin(conf) >= (int)thrbin[b]) {
        int p = atomicAdd(&ccnt[b], 1);
        if (p < CAND_CAP) cand[(size_t)b * CAND_CAP + p] = key;
    }
}

// Per-batch exact top-K over the small candidate set (radix select + bitonic sort).
__global__ void k_topk(u64* __restrict__ cand, const int* __restrict__ ccnt,
                       u64* __restrict__ bufA, u64* __restrict__ selected) {
    int b = blockIdx.x;
    int tid = threadIdx.x;
    __shared__ int hist[256];
    __shared__ int sh_split, sh_above, sh_selc, sh_candc;
    u64* sel = selected + b * KSEL;
    u64* pcur = cand + (size_t)b * CAND_CAP;
    u64* pnxt = bufA + (size_t)b * CAND_CAP;
    int n = ccnt[b];
    if (n > CAND_CAP) n = CAND_CAP;
    int need = KSEL, nsel = 0;

    for (int byte = 7; byte >= 0; byte--) {
        if (need <= 0) break;
        if (n <= need) {
            for (int idx = tid; idx < n; idx += blockDim.x) sel[nsel + idx] = pcur[idx];
            nsel += n; need -= n; n = 0;
            break;
        }
        hist[tid] = 0;
        __syncthreads();
        int shift = byte * 8;
        for (int idx = tid; idx < n; idx += blockDim.x)
            atomicAdd(&hist[(int)((pcur[idx] >> shift) & 255)], 1);
        __syncthreads();
        if (tid == 0) {
            int above = 0, s = 255;
            for (; s > 0; s--) {
                if (above + hist[s] >= need) break;
                above += hist[s];
            }
            sh_split = s; sh_above = above; sh_selc = 0; sh_candc = 0;
        }
        __syncthreads();
        int s = sh_split;
        for (int idx = tid; idx < n; idx += blockDim.x) {
            u64 e = pcur[idx];
            int bv = (int)((e >> shift) & 255);
            if (bv > s) { int p = atomicAdd(&sh_selc, 1); sel[nsel + p] = e; }
            else if (bv == s) { int p = atomicAdd(&sh_candc, 1); pnxt[p] = e; }
        }
        __syncthreads();
        nsel += sh_above; need -= sh_above; n = sh_candc;
        u64* t = pcur; pcur = pnxt; pnxt = t;
        __syncthreads();
    }
    if (need > 0 && n > 0) {
        int take = need < n ? need : n;
        for (int idx = tid; idx < take; idx += blockDim.x) sel[nsel + idx] = pcur[idx];
        nsel += take;
    }
    for (int idx = nsel + tid; idx < KSEL; idx += blockDim.x) sel[idx] = 0;
    __syncthreads();

    __shared__ u64 sk[KSEL];
    if (tid < KSEL) sk[tid] = sel[tid];
    __syncthreads();
    for (int k = 2; k <= KSEL; k <<= 1) {
        for (int j = k >> 1; j > 0; j >>= 1) {
            if (tid < KSEL) {
                int ixj = tid ^ j;
                if (ixj > tid) {
                    u64 a = sk[tid], c2 = sk[ixj];
                    bool upper = (tid & k) != 0;
                    if (upper ? (a > c2) : (a < c2)) { sk[tid] = c2; sk[ixj] = a; }
                }
            }
            __syncthreads();
        }
    }
    if (tid < KSEL) sel[tid] = sk[tid];
}

// Wave-per-peak finalize: parallel probes, coalesced feats gather, shfl GEMV.
__global__ void k_final(const int* __restrict__ coords, const float* __restrict__ feats,
                        const float* __restrict__ scores, const float* __restrict__ W,
                        const float* __restrict__ bias, const float* __restrict__ background,
                        const u64* __restrict__ tab, const u64* __restrict__ selected,
                        float* __restrict__ out, int N) {
    int gw = (blockIdx.x * blockDim.x + threadIdx.x) >> 6;
    int lane = threadIdx.x & 63;
    float* full = out + NB * KSEL + (size_t)N * 32;
    if (gw >= NB * KSEL) {
        int b = gw - NB * KSEL;
        if (b < NB && lane < 32)
            full[(size_t)(b * (KSEL + 1)) * 32 + lane] = background[lane];
        return;
    }
    int b = gw >> 7, k = gw & 127;
    u64 key = selected[gw];
    float* row = full + (size_t)(b * (KSEL + 1) + 1 + k) * 32;
    if (key == 0ull) {
        if (lane == 0) out[gw] = 0.f;
        if (lane < 32) row[lane] = 0.f;
        return;
    }
    float conf = __uint_as_float((u32)(key >> 32));
    int i = (int)(~(u32)key);
    if (lane == 0) out[gw] = conf;
    int4 c = ((const int4*)coords)[i];
    int kb = ((c.x * S + c.y) * S + c.z) * S + c.w;
    int j = -1; bool hit = false;
    if (lane < 27) {
        int dx = lane / 9 - 1, r = lane % 9;
        int dy = r / 3 - 1, dz = r % 3 - 1;
        int nx = c.y + dx, ny = c.z + dy, nz = c.w + dz;
        if ((unsigned)nx < S && (unsigned)ny < S && (unsigned)nz < S) {
            j = tab_lookup(tab, kb + dx * (S * S) + dy * S + dz);
            if (j >= 0) hit = scores[j] > TAU;
        }
    }
    u64 hm = __ballot(hit);
    int c27 = __popcll(hm);
    float fsum = 0.f;
    u64 m = hm;
    while (m) {
        int src = __ffsll((long long)m) - 1;
        m &= m - 1;
        int jj = __shfl(j, src);
        fsum += feats[(size_t)jj * 64 + lane];
    }
    float favg = fsum / fmaxf((float)c27, 1.0f);
    int d = lane & 31;
    float acc = bias[d];
    #pragma unroll
    for (int l = 0; l < 64; l++) {
        float fl = __shfl(favg, l);
        acc = fmaf(fl, W[l * 32 + d], acc);
    }
    float ss = acc * acc;
    #pragma unroll
    for (int off = 1; off < 32; off <<= 1) ss += __shfl_xor(ss, off);
    float inv = 1.0f / fmaxf(sqrtf(ss), 1e-12f);
    if (lane < 32) row[lane] = acc * inv;
}

extern "C" void kernel_launch(void* const* d_in, const int* in_sizes, int n_in,
                              void* d_out, int out_size, void* d_ws, size_t ws_size,
                              hipStream_t stream) {
    const int* coords = (const int*)d_in[0];
    const float* feats = (const float*)d_in[1];
    const float* scores = (const float*)d_in[2];
    const float* W = (const float*)d_in[3];
    const float* bias = (const float*)d_in[4];
    const float* background = (const float*)d_in[5];
    int N = in_sizes[0] / 4;
    float* out = (float*)d_out;
    int pcap = N / 2;

    char* ws = (char*)d_ws;
    size_t off = 0;
    u64* tab = (u64*)(ws + off); off += (size_t)TAB_SZ * 8;
    u64* tabc = (u64*)(ws + off); off += (size_t)TAB_SZ * 8;
    u32* bm = (u32*)(ws + off); off += (size_t)BM_WORDS * 4;
    int* hist = (int*)(ws + off); off += (size_t)NB * NBINS * 4;
    int* cnt = (int*)(ws + off); off += 256;
    int* ccnt = (int*)(ws + off); off += 256;
    u32* thrbin = (u32*)(ws + off); off += 256;
    u64* peaks = (u64*)(ws + off); off += (size_t)NB * pcap * 8;
    u64* cand = (u64*)(ws + off); off += (size_t)NB * CAND_CAP * 8;
    u64* bufA = (u64*)(ws + off); off += (size_t)NB * CAND_CAP * 8;
    u64* selected = (u64*)(ws + off); off += (size_t)NB * KSEL * 8;

    k_init<<<TAB_SZ / 256, 256, 0, stream>>>(tab, bm, cnt, hist, ccnt, thrbin);
    k_insert<<<(N + 255) / 256, 256, 0, stream>>>(coords, tab, N);
    k_tabpass<<<TAB_SZ / 256, 256, 0, stream>>>(scores, tab, tabc, bm);
    k_main<<<(N + 255) / 256, 256, 0, stream>>>(coords, feats, scores, W, bias, tabc, bm,
                                                peaks, cnt, hist, out + NB * KSEL, N, pcap);
    k_thresh<<<1, 256, 0, stream>>>(hist, cnt, thrbin, pcap);
    k_compact<<<(NB * pcap + 255) / 256, 256, 0, stream>>>(peaks, cnt, thrbin, cand, ccnt, pcap);
    k_topk<<<NB, 256, 0, stream>>>(cand, ccnt, bufA, selected);
    k_final<<<(NB * KSEL + NB + 3) / 4, 256, 0, stream>>>(coords, feats, scores, W, bias,
                                                          background, tab, selected, out, N);
}

// Round 5
// 371.083 us; speedup vs baseline: 11.6940x; 2.0687x over previous
//
#include <hip/hip_runtime.h>
#include <math.h>

#define S 256
#define NB 4
#define TAU 0.1f
#define KSEL 128
#define LOG_TAB 21
#define TAB_SZ (1u << LOG_TAB)
#define TAB_MASK (TAB_SZ - 1)
#define EMPTY64 0xFFFFFFFFFFFFFFFFull
#define BM_WORDS (1u << 21)   // 4*256^3 bits / 32
#define NBINS 8192
#define BIN_BASE 0x3D800      // (0x3D800000 >> 12), conf floor 0.0625 < TAU
#define CAND_CAP 4096
#define CPAD 32               // ints per counter slot -> one 128B line each

typedef unsigned long long u64;
typedef unsigned int u32;

__device__ __forceinline__ u32 hash_key(int key) {
    u32 h = (u32)key * 0x9E3779B1u;
    h ^= h >> 15;
    return h & TAB_MASK;
}

__device__ __forceinline__ int conf_bin(float conf) {
    int bin = (int)(__float_as_uint(conf) >> 12) - BIN_BASE;
    return bin < 0 ? 0 : (bin > NBINS - 1 ? NBINS - 1 : bin);
}

__global__ void k_init(u64* __restrict__ tab, u32* __restrict__ bm, int* __restrict__ cnt,
                       int* __restrict__ hist, int* __restrict__ ccnt, u32* __restrict__ thrbin) {
    int i = blockIdx.x * blockDim.x + threadIdx.x;
    if (i < (int)TAB_SZ) tab[i] = EMPTY64;
    if (i < (int)BM_WORDS) bm[i] = 0u;
    if (i < NB * NBINS) hist[i] = 0;
    if (i < NB * CPAD) { cnt[i] = 0; ccnt[i] = 0; }
    if (i < NB) thrbin[i] = 0;
}

__global__ void k_insert(const int* __restrict__ coords, u64* __restrict__ tab, int N) {
    int i = blockIdx.x * blockDim.x + threadIdx.x;
    if (i >= N) return;
    int4 c = ((const int4*)coords)[i];
    int key = ((c.x * S + c.y) * S + c.z) * S + c.w;
    u64 ins = ((u64)(u32)key << 32) | (u32)i;
    u32 slot = hash_key(key);
    for (;;) {
        u64 e = tab[slot];
        if ((u32)(e >> 32) == (u32)key) { atomicMin(&tab[slot], ins); return; }
        if (e == EMPTY64) {
            u64 prev = atomicCAS(&tab[slot], EMPTY64, ins);
            if (prev == EMPTY64) return;
            if ((u32)(prev >> 32) == (u32)key) { atomicMin(&tab[slot], ins); return; }
        }
        slot = (slot + 1) & TAB_MASK;
    }
}

// tabc[slot]=(key<<32)|conf_bits of representative (min index); set bm bit if conf>TAU.
__global__ void k_tabpass(const float* __restrict__ scores, const u64* __restrict__ tab,
                          u64* __restrict__ tabc, u32* __restrict__ bm) {
    int s = blockIdx.x * blockDim.x + threadIdx.x;
    if (s >= (int)TAB_SZ) return;
    u64 e = tab[s];
    if (e == EMPTY64) { tabc[s] = EMPTY64; return; }
    u32 key = (u32)(e >> 32);
    int j = (int)(u32)e;
    float c = scores[j];
    tabc[s] = ((u64)key << 32) | __float_as_uint(c);
    if (c > TAU) atomicOr(&bm[key >> 5], 1u << (key & 31));
}

__device__ __forceinline__ int tab_lookup(const u64* __restrict__ tab, int key) {
    u32 slot = hash_key(key);
    for (;;) {
        u64 e = tab[slot];
        if ((u32)(e >> 32) == (u32)key) return (int)(u32)e;
        if (e == EMPTY64) return -1;
        slot = (slot + 1) & TAB_MASK;
    }
}

__device__ __forceinline__ float probe_conf(const u64* __restrict__ tabc, int key) {
    u32 slot = hash_key(key);
    for (;;) {
        u64 e = tabc[slot];
        if ((u32)(e >> 32) == (u32)key) return __uint_as_float((u32)e);
        if (e == EMPTY64) return -INFINITY;
        slot = (slot + 1) & TAB_MASK;
    }
}

// Peak detect (z-packed bitmask + sparse probes) + hist + block-aggregated compaction.
__global__ void k_peak(const int* __restrict__ coords, const float* __restrict__ scores,
                       const u64* __restrict__ tabc, const u32* __restrict__ bm,
                       u64* __restrict__ peaks, int* __restrict__ cnt, int* __restrict__ hist,
                       int N, int pcap) {
    int i = blockIdx.x * blockDim.x + threadIdx.x;
    bool alive = (i < N);
    int ii = alive ? i : 0;
    int4 c = ((const int4*)coords)[ii];
    float conf = alive ? scores[ii] : -1.0f;
    int kb = ((c.x * S + c.y) * S + c.z) * S + c.w;
    bool ispeak = false;
    if (alive && conf > TAU) {
        u32 m27 = 0;
        u32 vzm = (u32)((c.w > 0) ? 1 : 0) | 2u | (u32)((c.w < S - 1) ? 4 : 0);
        #pragma unroll
        for (int dx = -1; dx <= 1; dx++) {
            if ((unsigned)(c.y + dx) >= S) continue;
            #pragma unroll
            for (int dy = -1; dy <= 1; dy++) {
                if ((unsigned)(c.z + dy) >= S) continue;
                int nk = kb + dx * (S * S) + dy * S;   // center-z key of this column
                u32 idx = (u32)nk >> 5;
                int sft = nk & 31;
                u32 w0 = bm[idx];
                u32 b3;
                if (sft >= 1 && sft <= 30) {
                    b3 = (w0 >> (sft - 1)) & 7u;
                } else if (sft == 0) {
                    u32 wm = (nk >= 32) ? bm[idx - 1] : 0u;
                    b3 = ((wm >> 31) & 1u) | ((w0 & 3u) << 1);
                } else { // sft == 31
                    u32 wp = (idx + 1 < BM_WORDS) ? bm[idx + 1] : 0u;
                    b3 = ((w0 >> 30) & 3u) | ((wp & 1u) << 2);
                }
                b3 &= vzm;
                int p = ((dx + 1) * 3 + (dy + 1)) * 3;
                m27 |= b3 << p;
            }
        }
        float hmax = -INFINITY;
        while (m27) {
            int q = __builtin_ctz(m27);
            m27 &= m27 - 1;
            int dx = q / 9 - 1;
            int r = q % 9;
            int dy = r / 3 - 1, dz = r % 3 - 1;
            float cj = probe_conf(tabc, kb + dx * (S * S) + dy * S + dz);
            hmax = fmaxf(hmax, cj);
        }
        ispeak = (hmax == conf);
    }

    if (ispeak) atomicAdd(&hist[c.x * NBINS + conf_bin(conf)], 1);

    // block-aggregated compaction: 4 padded atomics per BLOCK
    __shared__ int wcnt[4][NB];
    __shared__ int bbase[NB];
    int w = threadIdx.x >> 6;
    int lane = threadIdx.x & 63;
    u64 lmask_lt = (lane == 63) ? 0x7FFFFFFFFFFFFFFFull : ((1ull << lane) - 1ull);
    u64 mb[NB];
    #pragma unroll
    for (int b = 0; b < NB; b++) {
        mb[b] = __ballot(ispeak && (c.x == b));
        if (lane == 0) wcnt[w][b] = __popcll(mb[b]);
    }
    __syncthreads();
    if (threadIdx.x < NB) {
        int b = threadIdx.x;
        int tot = wcnt[0][b] + wcnt[1][b] + wcnt[2][b] + wcnt[3][b];
        bbase[b] = tot > 0 ? atomicAdd(&cnt[b * CPAD], tot) : 0;
    }
    __syncthreads();
    if (ispeak) {
        int b = c.x;
        int pre = 0;
        for (int w2 = 0; w2 < w; w2++) pre += wcnt[w2][b];
        int rank = __popcll(mb[b] & lmask_lt);
        int pidx = bbase[b] + pre + rank;
        if (pidx < pcap)
            peaks[(size_t)b * pcap + pidx] =
                ((u64)__float_as_uint(conf) << 32) | (u32)(~(u32)i);
    }
}

// Pure streaming GEMV: voxel_desc = l2norm(feats @ W + b)
__global__ void k_desc(const float* __restrict__ feats, const float* __restrict__ W,
                       const float* __restrict__ bias, float* __restrict__ voxel_desc, int N) {
    int i = blockIdx.x * blockDim.x + threadIdx.x;
    if (i >= N) return;
    const float4* f4 = (const float4*)(feats + (size_t)i * 64);
    float acc[32];
    #pragma unroll
    for (int d = 0; d < 32; d++) acc[d] = bias[d];
    #pragma unroll
    for (int l4 = 0; l4 < 16; l4++) {
        float4 f = f4[l4];
        #pragma unroll
        for (int d = 0; d < 32; d++) {
            acc[d] = fmaf(f.x, W[(l4 * 4 + 0) * 32 + d], acc[d]);
            acc[d] = fmaf(f.y, W[(l4 * 4 + 1) * 32 + d], acc[d]);
            acc[d] = fmaf(f.z, W[(l4 * 4 + 2) * 32 + d], acc[d]);
            acc[d] = fmaf(f.w, W[(l4 * 4 + 3) * 32 + d], acc[d]);
        }
    }
    float ss = 0.f;
    #pragma unroll
    for (int d = 0; d < 32; d++) ss += acc[d] * acc[d];
    float inv = 1.0f / fmaxf(sqrtf(ss), 1e-12f);
    float4* out4 = (float4*)(voxel_desc + (size_t)i * 32);
    #pragma unroll
    for (int q = 0; q < 8; q++) {
        float4 o;
        o.x = acc[q * 4 + 0] * inv; o.y = acc[q * 4 + 1] * inv;
        o.z = acc[q * 4 + 2] * inv; o.w = acc[q * 4 + 3] * inv;
        out4[q] = o;
    }
}

// One block; wave b finds per-batch threshold bin (count of bins >= thr covers K).
__global__ void k_thresh(const int* __restrict__ hist, const int* __restrict__ cnt,
                         u32* __restrict__ thrbin, int pcap) {
    int w = threadIdx.x >> 6;
    int lane = threadIdx.x & 63;
    if (w >= NB) return;
    int n = cnt[w * CPAD]; if (n > pcap) n = pcap;
    int need = n < KSEL ? n : KSEL;
    const int* h = hist + w * NBINS;
    int running = 0;
    u32 thr = 0;
    for (int hi = NBINS - 64; hi >= 0; hi -= 64) {
        int v = h[hi + lane];
        int s = v;   // inclusive suffix scan: s(lane) = sum_{l>=lane} v
        #pragma unroll
        for (int off = 1; off < 64; off <<= 1) {
            int o = __shfl_down(s, off);
            if (lane + off < 64) s += o;
        }
        int csum = __shfl(s, 0);
        if (running + csum >= need) {
            u64 m = __ballot(running + s >= need);
            int top = 63 - __builtin_clzll(m);
            thr = (u32)(hi + top);
            break;
        }
        running += csum;
    }
    if (lane == 0) thrbin[w] = thr;
}

__global__ void k_compact(const u64* __restrict__ peaks, const int* __restrict__ cnt,
                          const u32* __restrict__ thrbin, u64* __restrict__ cand,
                          int* __restrict__ ccnt, int pcap) {
    int t = blockIdx.x * blockDim.x + threadIdx.x;
    int b = t / pcap;
    if (b >= NB) return;
    int e = t % pcap;
    int n = cnt[b * CPAD]; if (n > pcap) n = pcap;
    if (e >= n) return;
    u64 key = peaks[(size_t)b * pcap + e];
    float conf = __uint_as_float((u32)(key >> 32));
    if (conf_bin(conf) >= (int)thrbin[b]) {
        int p = atomicAdd(&ccnt[b * CPAD], 1);
        if (p < CAND_CAP) cand[(size_t)b * CAND_CAP + p] = key;
    }
}

// Per-batch exact top-K over the small candidate set (radix select + bitonic sort).
__global__ void k_topk(u64* __restrict__ cand, const int* __restrict__ ccnt,
                       u64* __restrict__ bufA, u64* __restrict__ selected) {
    int b = blockIdx.x;
    int tid = threadIdx.x;
    __shared__ int hist[256];
    __shared__ int sh_split, sh_above, sh_selc, sh_candc;
    u64* sel = selected + b * KSEL;
    u64* pcur = cand + (size_t)b * CAND_CAP;
    u64* pnxt = bufA + (size_t)b * CAND_CAP;
    int n = ccnt[b * CPAD];
    if (n > CAND_CAP) n = CAND_CAP;
    int need = KSEL, nsel = 0;

    for (int byte = 7; byte >= 0; byte--) {
        if (need <= 0) break;
        if (n <= need) {
            for (int idx = tid; idx < n; idx += blockDim.x) sel[nsel + idx] = pcur[idx];
            nsel += n; need -= n; n = 0;
            break;
        }
        hist[tid] = 0;
        __syncthreads();
        int shift = byte * 8;
        for (int idx = tid; idx < n; idx += blockDim.x)
            atomicAdd(&hist[(int)((pcur[idx] >> shift) & 255)], 1);
        __syncthreads();
        if (tid == 0) {
            int above = 0, s = 255;
            for (; s > 0; s--) {
                if (above + hist[s] >= need) break;
                above += hist[s];
            }
            sh_split = s; sh_above = above; sh_selc = 0; sh_candc = 0;
        }
        __syncthreads();
        int s = sh_split;
        for (int idx = tid; idx < n; idx += blockDim.x) {
            u64 e = pcur[idx];
            int bv = (int)((e >> shift) & 255);
            if (bv > s) { int p = atomicAdd(&sh_selc, 1); sel[nsel + p] = e; }
            else if (bv == s) { int p = atomicAdd(&sh_candc, 1); pnxt[p] = e; }
        }
        __syncthreads();
        nsel += sh_above; need -= sh_above; n = sh_candc;
        u64* t = pcur; pcur = pnxt; pnxt = t;
        __syncthreads();
    }
    if (need > 0 && n > 0) {
        int take = need < n ? need : n;
        for (int idx = tid; idx < take; idx += blockDim.x) sel[nsel + idx] = pcur[idx];
        nsel += take;
    }
    for (int idx = nsel + tid; idx < KSEL; idx += blockDim.x) sel[idx] = 0;
    __syncthreads();

    __shared__ u64 sk[KSEL];
    if (tid < KSEL) sk[tid] = sel[tid];
    __syncthreads();
    for (int k = 2; k <= KSEL; k <<= 1) {
        for (int j = k >> 1; j > 0; j >>= 1) {
            if (tid < KSEL) {
                int ixj = tid ^ j;
                if (ixj > tid) {
                    u64 a = sk[tid], c2 = sk[ixj];
                    bool upper = (tid & k) != 0;
                    if (upper ? (a > c2) : (a < c2)) { sk[tid] = c2; sk[ixj] = a; }
                }
            }
            __syncthreads();
        }
    }
    if (tid < KSEL) sel[tid] = sk[tid];
}

// Wave-per-peak finalize: parallel probes, coalesced feats gather, shfl GEMV.
__global__ void k_final(const int* __restrict__ coords, const float* __restrict__ feats,
                        const float* __restrict__ scores, const float* __restrict__ W,
                        const float* __restrict__ bias, const float* __restrict__ background,
                        const u64* __restrict__ tab, const u64* __restrict__ selected,
                        float* __restrict__ out, int N) {
    int gw = (blockIdx.x * blockDim.x + threadIdx.x) >> 6;
    int lane = threadIdx.x & 63;
    float* full = out + NB * KSEL + (size_t)N * 32;
    if (gw >= NB * KSEL) {
        int b = gw - NB * KSEL;
        if (b < NB && lane < 32)
            full[(size_t)(b * (KSEL + 1)) * 32 + lane] = background[lane];
        return;
    }
    int b = gw >> 7, k = gw & 127;
    u64 key = selected[gw];
    float* row = full + (size_t)(b * (KSEL + 1) + 1 + k) * 32;
    if (key == 0ull) {
        if (lane == 0) out[gw] = 0.f;
        if (lane < 32) row[lane] = 0.f;
        return;
    }
    float conf = __uint_as_float((u32)(key >> 32));
    int i = (int)(~(u32)key);
    if (lane == 0) out[gw] = conf;
    int4 c = ((const int4*)coords)[i];
    int kb = ((c.x * S + c.y) * S + c.z) * S + c.w;
    int j = -1; bool hit = false;
    if (lane < 27) {
        int dx = lane / 9 - 1, r = lane % 9;
        int dy = r / 3 - 1, dz = r % 3 - 1;
        int nx = c.y + dx, ny = c.z + dy, nz = c.w + dz;
        if ((unsigned)nx < S && (unsigned)ny < S && (unsigned)nz < S) {
            j = tab_lookup(tab, kb + dx * (S * S) + dy * S + dz);
            if (j >= 0) hit = scores[j] > TAU;
        }
    }
    u64 hm = __ballot(hit);
    int c27 = __popcll(hm);
    float fsum = 0.f;
    u64 m = hm;
    while (m) {
        int src = __ffsll((long long)m) - 1;
        m &= m - 1;
        int jj = __shfl(j, src);
        fsum += feats[(size_t)jj * 64 + lane];
    }
    float favg = fsum / fmaxf((float)c27, 1.0f);
    int d = lane & 31;
    float acc = bias[d];
    #pragma unroll
    for (int l = 0; l < 64; l++) {
        float fl = __shfl(favg, l);
        acc = fmaf(fl, W[l * 32 + d], acc);
    }
    float ss = acc * acc;
    #pragma unroll
    for (int off = 1; off < 32; off <<= 1) ss += __shfl_xor(ss, off);
    float inv = 1.0f / fmaxf(sqrtf(ss), 1e-12f);
    if (lane < 32) row[lane] = acc * inv;
}

extern "C" void kernel_launch(void* const* d_in, const int* in_sizes, int n_in,
                              void* d_out, int out_size, void* d_ws, size_t ws_size,
                              hipStream_t stream) {
    const int* coords = (const int*)d_in[0];
    const float* feats = (const float*)d_in[1];
    const float* scores = (const float*)d_in[2];
    const float* W = (const float*)d_in[3];
    const float* bias = (const float*)d_in[4];
    const float* background = (const float*)d_in[5];
    int N = in_sizes[0] / 4;
    float* out = (float*)d_out;
    int pcap = N / 2;

    char* ws = (char*)d_ws;
    size_t off = 0;
    u64* tab = (u64*)(ws + off); off += (size_t)TAB_SZ * 8;
    u64* tabc = (u64*)(ws + off); off += (size_t)TAB_SZ * 8;
    u32* bm = (u32*)(ws + off); off += (size_t)BM_WORDS * 4;
    int* hist = (int*)(ws + off); off += (size_t)NB * NBINS * 4;
    int* cnt = (int*)(ws + off); off += (size_t)NB * CPAD * 4;
    int* ccnt = (int*)(ws + off); off += (size_t)NB * CPAD * 4;
    u32* thrbin = (u32*)(ws + off); off += 256;
    u64* peaks = (u64*)(ws + off); off += (size_t)NB * pcap * 8;
    u64* cand = (u64*)(ws + off); off += (size_t)NB * CAND_CAP * 8;
    u64* bufA = (u64*)(ws + off); off += (size_t)NB * CAND_CAP * 8;
    u64* selected = (u64*)(ws + off); off += (size_t)NB * KSEL * 8;

    k_init<<<TAB_SZ / 256, 256, 0, stream>>>(tab, bm, cnt, hist, ccnt, thrbin);
    k_insert<<<(N + 255) / 256, 256, 0, stream>>>(coords, tab, N);
    k_tabpass<<<TAB_SZ / 256, 256, 0, stream>>>(scores, tab, tabc, bm);
    k_peak<<<(N + 255) / 256, 256, 0, stream>>>(coords, scores, tabc, bm,
                                                peaks, cnt, hist, N, pcap);
    k_desc<<<(N + 255) / 256, 256, 0, stream>>>(feats, W, bias, out + NB * KSEL, N);
    k_thresh<<<1, 256, 0, stream>>>(hist, cnt, thrbin, pcap);
    k_compact<<<(NB * pcap + 255) / 256, 256, 0, stream>>>(peaks, cnt, thrbin, cand, ccnt, pcap);
    k_topk<<<NB, 256, 0, stream>>>(cand, ccnt, bufA, selected);
    k_final<<<(NB * KSEL + NB + 3) / 4, 256, 0, stream>>>(coords, feats, scores, W, bias,
                                                          background, tab, selected, out, N);
}

// Round 6
// 368.501 us; speedup vs baseline: 11.7760x; 1.0070x over previous
//
#include <hip/hip_runtime.h>
#include <math.h>

#define S 256
#define NB 4
#define TAU 0.1f
#define KSEL 128
#define LOG_TAB 21
#define TAB_SZ (1u << LOG_TAB)
#define TAB_MASK (TAB_SZ - 1)
#define EMPTY64 0xFFFFFFFFFFFFFFFFull
#define BM_WORDS (1u << 21)   // 4*256^3 bits / 32
#define NBINS 8192
#define BIN_BASE 0x3D800      // (0x3D800000 >> 12), conf floor 0.0625 < TAU
#define CAND_CAP 4096
#define CPAD 32               // ints per counter slot -> one 128B line each

typedef unsigned long long u64;
typedef unsigned int u32;

__device__ __forceinline__ u32 hash_key(int key) {
    u32 h = (u32)key * 0x9E3779B1u;
    h ^= h >> 15;
    return h & TAB_MASK;
}

__device__ __forceinline__ int conf_bin(float conf) {
    int bin = (int)(__float_as_uint(conf) >> 12) - BIN_BASE;
    return bin < 0 ? 0 : (bin > NBINS - 1 ? NBINS - 1 : bin);
}

__global__ void k_init(u64* __restrict__ tab, u32* __restrict__ bm, int* __restrict__ cnt,
                       int* __restrict__ hist, int* __restrict__ ccnt, u32* __restrict__ thrbin) {
    int i = blockIdx.x * blockDim.x + threadIdx.x;
    if (i < (int)TAB_SZ) tab[i] = EMPTY64;
    if (i < (int)BM_WORDS) bm[i] = 0u;
    if (i < NB * NBINS) hist[i] = 0;
    if (i < NB * CPAD) { cnt[i] = 0; ccnt[i] = 0; }
    if (i < NB) thrbin[i] = 0;
}

// Insert (key -> min index) AND set bm bit with own conf. bm = OR over dups with
// conf>TAU: superset of "rep conf>TAU"; false positives only ever add cj<=TAU<conf
// to hmax, which cannot change the (hmax==conf) peak decision.
__global__ void k_insert(const int* __restrict__ coords, const float* __restrict__ scores,
                         u64* __restrict__ tab, u32* __restrict__ bm, int N) {
    int i = blockIdx.x * blockDim.x + threadIdx.x;
    if (i >= N) return;
    int4 c = ((const int4*)coords)[i];
    float conf = scores[i];
    int key = ((c.x * S + c.y) * S + c.z) * S + c.w;
    if (conf > TAU) atomicOr(&bm[(u32)key >> 5], 1u << (key & 31));
    u64 ins = ((u64)(u32)key << 32) | (u32)i;
    u32 slot = hash_key(key);
    for (;;) {
        u64 e = tab[slot];
        if ((u32)(e >> 32) == (u32)key) { atomicMin(&tab[slot], ins); return; }
        if (e == EMPTY64) {
            u64 prev = atomicCAS(&tab[slot], EMPTY64, ins);
            if (prev == EMPTY64) return;
            if ((u32)(prev >> 32) == (u32)key) { atomicMin(&tab[slot], ins); return; }
        }
        slot = (slot + 1) & TAB_MASK;
    }
}

__device__ __forceinline__ int tab_lookup(const u64* __restrict__ tab, int key) {
    u32 slot = hash_key(key);
    for (;;) {
        u64 e = tab[slot];
        if ((u32)(e >> 32) == (u32)key) return (int)(u32)e;
        if (e == EMPTY64) return -1;
        slot = (slot + 1) & TAB_MASK;
    }
}

// Peak detect (z-packed bitmask + sparse probes) + hist + block-aggregated compaction.
__global__ void k_peak(const int* __restrict__ coords, const float* __restrict__ scores,
                       const u64* __restrict__ tab, const u32* __restrict__ bm,
                       u64* __restrict__ peaks, int* __restrict__ cnt, int* __restrict__ hist,
                       int N, int pcap) {
    int i = blockIdx.x * blockDim.x + threadIdx.x;
    bool alive = (i < N);
    int ii = alive ? i : 0;
    int4 c = ((const int4*)coords)[ii];
    float conf = alive ? scores[ii] : -1.0f;
    int kb = ((c.x * S + c.y) * S + c.z) * S + c.w;
    bool ispeak = false;
    if (alive && conf > TAU) {
        u32 m27 = 0;
        u32 vzm = (u32)((c.w > 0) ? 1 : 0) | 2u | (u32)((c.w < S - 1) ? 4 : 0);
        #pragma unroll
        for (int dx = -1; dx <= 1; dx++) {
            if ((unsigned)(c.y + dx) >= S) continue;
            #pragma unroll
            for (int dy = -1; dy <= 1; dy++) {
                if ((unsigned)(c.z + dy) >= S) continue;
                int nk = kb + dx * (S * S) + dy * S;   // center-z key of this column
                u32 idx = (u32)nk >> 5;
                int sft = nk & 31;
                u32 w0 = bm[idx];
                u32 b3;
                if (sft >= 1 && sft <= 30) {
                    b3 = (w0 >> (sft - 1)) & 7u;
                } else if (sft == 0) {
                    u32 wm = (nk >= 32) ? bm[idx - 1] : 0u;
                    b3 = ((wm >> 31) & 1u) | ((w0 & 3u) << 1);
                } else { // sft == 31
                    u32 wp = (idx + 1 < BM_WORDS) ? bm[idx + 1] : 0u;
                    b3 = ((w0 >> 30) & 3u) | ((wp & 1u) << 2);
                }
                b3 &= vzm;
                int p = ((dx + 1) * 3 + (dy + 1)) * 3;
                m27 |= b3 << p;
            }
        }
        float hmax = -INFINITY;
        while (m27) {
            int q = __builtin_ctz(m27);
            m27 &= m27 - 1;
            int dx = q / 9 - 1;
            int r = q % 9;
            int dy = r / 3 - 1, dz = r % 3 - 1;
            int j = tab_lookup(tab, kb + dx * (S * S) + dy * S + dz);
            if (j >= 0) hmax = fmaxf(hmax, scores[j]); // cj<=TAU contributions harmless
        }
        ispeak = (hmax == conf);
    }

    if (ispeak) atomicAdd(&hist[c.x * NBINS + conf_bin(conf)], 1);

    // block-aggregated compaction: 4 padded atomics per BLOCK
    __shared__ int wcnt[4][NB];
    __shared__ int bbase[NB];
    int w = threadIdx.x >> 6;
    int lane = threadIdx.x & 63;
    u64 lmask_lt = (lane == 63) ? 0x7FFFFFFFFFFFFFFFull : ((1ull << lane) - 1ull);
    u64 mb[NB];
    #pragma unroll
    for (int b = 0; b < NB; b++) {
        mb[b] = __ballot(ispeak && (c.x == b));
        if (lane == 0) wcnt[w][b] = __popcll(mb[b]);
    }
    __syncthreads();
    if (threadIdx.x < NB) {
        int b = threadIdx.x;
        int tot = wcnt[0][b] + wcnt[1][b] + wcnt[2][b] + wcnt[3][b];
        bbase[b] = tot > 0 ? atomicAdd(&cnt[b * CPAD], tot) : 0;
    }
    __syncthreads();
    if (ispeak) {
        int b = c.x;
        int pre = 0;
        for (int w2 = 0; w2 < w; w2++) pre += wcnt[w2][b];
        int rank = __popcll(mb[b] & lmask_lt);
        int pidx = bbase[b] + pre + rank;
        if (pidx < pcap)
            peaks[(size_t)b * pcap + pidx] =
                ((u64)__float_as_uint(conf) << 32) | (u32)(~(u32)i);
    }
}

// LDS-staged streaming GEMV: voxel_desc = l2norm(feats @ W + b).
// 2 waves/block, each wave owns a 64-row tile (16KB contiguous gmem).
__global__ __launch_bounds__(128) void k_desc(const float* __restrict__ feats,
                       const float* __restrict__ W, const float* __restrict__ bias,
                       float* __restrict__ voxel_desc, int N) {
    __shared__ float lw[2][64 * 65];
    int w = threadIdx.x >> 6;
    int lane = threadIdx.x & 63;
    int tile = blockIdx.x * 2 + w;
    int r0 = tile * 64;
    float* L = lw[w];
    // stage: 16 coalesced float4 loads per lane (1KB/instr, contiguous)
    const float4* src = (const float4*)(feats + (size_t)r0 * 64);
    int maxq = (N - r0) * 16;   // remaining float4s in this tile's range
    #pragma unroll
    for (int k = 0; k < 16; k++) {
        int q = k * 64 + lane;
        float4 v = (q < maxq) ? src[q] : float4{0.f, 0.f, 0.f, 0.f};
        int row = q >> 4, col = (q & 15) * 4;
        L[row * 65 + col + 0] = v.x;
        L[row * 65 + col + 1] = v.y;
        L[row * 65 + col + 2] = v.z;
        L[row * 65 + col + 3] = v.w;
    }
    __syncthreads();
    int i = r0 + lane;
    if (i >= N) return;
    const float* f = L + lane * 65;   // bank (lane+e)%32 -> 2 lanes/bank, free
    float acc[32];
    #pragma unroll
    for (int d = 0; d < 32; d++) acc[d] = bias[d];
    #pragma unroll
    for (int l4 = 0; l4 < 16; l4++) {
        float f0 = f[l4 * 4 + 0], f1 = f[l4 * 4 + 1];
        float f2 = f[l4 * 4 + 2], f3 = f[l4 * 4 + 3];
        #pragma unroll
        for (int d = 0; d < 32; d++) {
            acc[d] = fmaf(f0, W[(l4 * 4 + 0) * 32 + d], acc[d]);
            acc[d] = fmaf(f1, W[(l4 * 4 + 1) * 32 + d], acc[d]);
            acc[d] = fmaf(f2, W[(l4 * 4 + 2) * 32 + d], acc[d]);
            acc[d] = fmaf(f3, W[(l4 * 4 + 3) * 32 + d], acc[d]);
        }
    }
    float ss = 0.f;
    #pragma unroll
    for (int d = 0; d < 32; d++) ss += acc[d] * acc[d];
    float inv = 1.0f / fmaxf(sqrtf(ss), 1e-12f);
    float4* out4 = (float4*)(voxel_desc + (size_t)i * 32);
    #pragma unroll
    for (int q = 0; q < 8; q++) {
        float4 o;
        o.x = acc[q * 4 + 0] * inv; o.y = acc[q * 4 + 1] * inv;
        o.z = acc[q * 4 + 2] * inv; o.w = acc[q * 4 + 3] * inv;
        out4[q] = o;   // each lane writes exactly one full 128B line
    }
}

// One block; wave b finds per-batch threshold bin (count of bins >= thr covers K).
__global__ void k_thresh(const int* __restrict__ hist, const int* __restrict__ cnt,
                         u32* __restrict__ thrbin, int pcap) {
    int w = threadIdx.x >> 6;
    int lane = threadIdx.x & 63;
    if (w >= NB) return;
    int n = cnt[w * CPAD]; if (n > pcap) n = pcap;
    int need = n < KSEL ? n : KSEL;
    const int* h = hist + w * NBINS;
    int running = 0;
    u32 thr = 0;
    for (int hi = NBINS - 64; hi >= 0; hi -= 64) {
        int v = h[hi + lane];
        int s = v;   // inclusive suffix scan
        #pragma unroll
        for (int off = 1; off < 64; off <<= 1) {
            int o = __shfl_down(s, off);
            if (lane + off < 64) s += o;
        }
        int csum = __shfl(s, 0);
        if (running + csum >= need) {
            u64 m = __ballot(running + s >= need);
            int top = 63 - __builtin_clzll(m);
            thr = (u32)(hi + top);
            break;
        }
        running += csum;
    }
    if (lane == 0) thrbin[w] = thr;
}

__global__ void k_compact(const u64* __restrict__ peaks, const int* __restrict__ cnt,
                          const u32* __restrict__ thrbin, u64* __restrict__ cand,
                          int* __restrict__ ccnt, int pcap) {
    int t = blockIdx.x * blockDim.x + threadIdx.x;
    int b = t / pcap;
    if (b >= NB) return;
    int e = t % pcap;
    int n = cnt[b * CPAD]; if (n > pcap) n = pcap;
    if (e >= n) return;
    u64 key = peaks[(size_t)b * pcap + e];
    float conf = __uint_as_float((u32)(key >> 32));
    if (conf_bin(conf) >= (int)thrbin[b]) {
        int p = atomicAdd(&ccnt[b * CPAD], 1);
        if (p < CAND_CAP) cand[(size_t)b * CAND_CAP + p] = key;
    }
}

// Per-batch exact top-K over the small candidate set (radix select + bitonic sort).
__global__ void k_topk(u64* __restrict__ cand, const int* __restrict__ ccnt,
                       u64* __restrict__ bufA, u64* __restrict__ selected) {
    int b = blockIdx.x;
    int tid = threadIdx.x;
    __shared__ int hist[256];
    __shared__ int sh_split, sh_above, sh_selc, sh_candc;
    u64* sel = selected + b * KSEL;
    u64* pcur = cand + (size_t)b * CAND_CAP;
    u64* pnxt = bufA + (size_t)b * CAND_CAP;
    int n = ccnt[b * CPAD];
    if (n > CAND_CAP) n = CAND_CAP;
    int need = KSEL, nsel = 0;

    for (int byte = 7; byte >= 0; byte--) {
        if (need <= 0) break;
        if (n <= need) {
            for (int idx = tid; idx < n; idx += blockDim.x) sel[nsel + idx] = pcur[idx];
            nsel += n; need -= n; n = 0;
            break;
        }
        hist[tid] = 0;
        __syncthreads();
        int shift = byte * 8;
        for (int idx = tid; idx < n; idx += blockDim.x)
            atomicAdd(&hist[(int)((pcur[idx] >> shift) & 255)], 1);
        __syncthreads();
        if (tid == 0) {
            int above = 0, s = 255;
            for (; s > 0; s--) {
                if (above + hist[s] >= need) break;
                above += hist[s];
            }
            sh_split = s; sh_above = above; sh_selc = 0; sh_candc = 0;
        }
        __syncthreads();
        int s = sh_split;
        for (int idx = tid; idx < n; idx += blockDim.x) {
            u64 e = pcur[idx];
            int bv = (int)((e >> shift) & 255);
            if (bv > s) { int p = atomicAdd(&sh_selc, 1); sel[nsel + p] = e; }
            else if (bv == s) { int p = atomicAdd(&sh_candc, 1); pnxt[p] = e; }
        }
        __syncthreads();
        nsel += sh_above; need -= sh_above; n = sh_candc;
        u64* t = pcur; pcur = pnxt; pnxt = t;
        __syncthreads();
    }
    if (need > 0 && n > 0) {
        int take = need < n ? need : n;
        for (int idx = tid; idx < take; idx += blockDim.x) sel[nsel + idx] = pcur[idx];
        nsel += take;
    }
    for (int idx = nsel + tid; idx < KSEL; idx += blockDim.x) sel[idx] = 0;
    __syncthreads();

    __shared__ u64 sk[KSEL];
    if (tid < KSEL) sk[tid] = sel[tid];
    __syncthreads();
    for (int k = 2; k <= KSEL; k <<= 1) {
        for (int j = k >> 1; j > 0; j >>= 1) {
            if (tid < KSEL) {
                int ixj = tid ^ j;
                if (ixj > tid) {
                    u64 a = sk[tid], c2 = sk[ixj];
                    bool upper = (tid & k) != 0;
                    if (upper ? (a > c2) : (a < c2)) { sk[tid] = c2; sk[ixj] = a; }
                }
            }
            __syncthreads();
        }
    }
    if (tid < KSEL) sel[tid] = sk[tid];
}

// Wave-per-peak finalize: parallel probes, coalesced feats gather, shfl GEMV.
__global__ void k_final(const int* __restrict__ coords, const float* __restrict__ feats,
                        const float* __restrict__ scores, const float* __restrict__ W,
                        const float* __restrict__ bias, const float* __restrict__ background,
                        const u64* __restrict__ tab, const u64* __restrict__ selected,
                        float* __restrict__ out, int N) {
    int gw = (blockIdx.x * blockDim.x + threadIdx.x) >> 6;
    int lane = threadIdx.x & 63;
    float* full = out + NB * KSEL + (size_t)N * 32;
    if (gw >= NB * KSEL) {
        int b = gw - NB * KSEL;
        if (b < NB && lane < 32)
            full[(size_t)(b * (KSEL + 1)) * 32 + lane] = background[lane];
        return;
    }
    int b = gw >> 7, k = gw & 127;
    u64 key = selected[gw];
    float* row = full + (size_t)(b * (KSEL + 1) + 1 + k) * 32;
    if (key == 0ull) {
        if (lane == 0) out[gw] = 0.f;
        if (lane < 32) row[lane] = 0.f;
        return;
    }
    float conf = __uint_as_float((u32)(key >> 32));
    int i = (int)(~(u32)key);
    if (lane == 0) out[gw] = conf;
    int4 c = ((const int4*)coords)[i];
    int kb = ((c.x * S + c.y) * S + c.z) * S + c.w;
    int j = -1; bool hit = false;
    if (lane < 27) {
        int dx = lane / 9 - 1, r = lane % 9;
        int dy = r / 3 - 1, dz = r % 3 - 1;
        int nx = c.y + dx, ny = c.z + dy, nz = c.w + dz;
        if ((unsigned)nx < S && (unsigned)ny < S && (unsigned)nz < S) {
            j = tab_lookup(tab, kb + dx * (S * S) + dy * S + dz);
            if (j >= 0) hit = scores[j] > TAU;
        }
    }
    u64 hm = __ballot(hit);
    int c27 = __popcll(hm);
    float fsum = 0.f;
    u64 m = hm;
    while (m) {
        int src = __ffsll((long long)m) - 1;
        m &= m - 1;
        int jj = __shfl(j, src);
        fsum += feats[(size_t)jj * 64 + lane];
    }
    float favg = fsum / fmaxf((float)c27, 1.0f);
    int d = lane & 31;
    float acc = bias[d];
    #pragma unroll
    for (int l = 0; l < 64; l++) {
        float fl = __shfl(favg, l);
        acc = fmaf(fl, W[l * 32 + d], acc);
    }
    float ss = acc * acc;
    #pragma unroll
    for (int off = 1; off < 32; off <<= 1) ss += __shfl_xor(ss, off);
    float inv = 1.0f / fmaxf(sqrtf(ss), 1e-12f);
    if (lane < 32) row[lane] = acc * inv;
}

extern "C" void kernel_launch(void* const* d_in, const int* in_sizes, int n_in,
                              void* d_out, int out_size, void* d_ws, size_t ws_size,
                              hipStream_t stream) {
    const int* coords = (const int*)d_in[0];
    const float* feats = (const float*)d_in[1];
    const float* scores = (const float*)d_in[2];
    const float* W = (const float*)d_in[3];
    const float* bias = (const float*)d_in[4];
    const float* background = (const float*)d_in[5];
    int N = in_sizes[0] / 4;
    float* out = (float*)d_out;
    int pcap = N / 2;

    char* ws = (char*)d_ws;
    size_t off = 0;
    u64* tab = (u64*)(ws + off); off += (size_t)TAB_SZ * 8;
    u32* bm = (u32*)(ws + off); off += (size_t)BM_WORDS * 4;
    int* hist = (int*)(ws + off); off += (size_t)NB * NBINS * 4;
    int* cnt = (int*)(ws + off); off += (size_t)NB * CPAD * 4;
    int* ccnt = (int*)(ws + off); off += (size_t)NB * CPAD * 4;
    u32* thrbin = (u32*)(ws + off); off += 256;
    u64* peaks = (u64*)(ws + off); off += (size_t)NB * pcap * 8;
    u64* cand = (u64*)(ws + off); off += (size_t)NB * CAND_CAP * 8;
    u64* bufA = (u64*)(ws + off); off += (size_t)NB * CAND_CAP * 8;
    u64* selected = (u64*)(ws + off); off += (size_t)NB * KSEL * 8;

    int nTiles = (N + 63) / 64;
    k_init<<<TAB_SZ / 256, 256, 0, stream>>>(tab, bm, cnt, hist, ccnt, thrbin);
    k_insert<<<(N + 255) / 256, 256, 0, stream>>>(coords, scores, tab, bm, N);
    k_peak<<<(N + 255) / 256, 256, 0, stream>>>(coords, scores, tab, bm,
                                                peaks, cnt, hist, N, pcap);
    k_desc<<<(nTiles + 1) / 2, 128, 0, stream>>>(feats, W, bias, out + NB * KSEL, N);
    k_thresh<<<1, 256, 0, stream>>>(hist, cnt, thrbin, pcap);
    k_compact<<<(NB * pcap + 255) / 256, 256, 0, stream>>>(peaks, cnt, thrbin, cand, ccnt, pcap);
    k_topk<<<NB, 256, 0, stream>>>(cand, ccnt, bufA, selected);
    k_final<<<(NB * KSEL + NB + 3) / 4, 256, 0, stream>>>(coords, feats, scores, W, bias,
                                                          background, tab, selected, out, N);
}